// Round 1
// baseline (4672.250 us; speedup 1.0000x reference)
//
#include <hip/hip_runtime.h>
#include <cmath>

// Problem constants
#define TT  8
#define NP  16000
#define NA  16000
#define NV  200
#define DIN 256
#define HH  256
#define KA  4
#define LL  5
#define BB  48000   // 3 * NP

// ---------------------------------------------------------------------------
// Embed GEMM: E = relu(X @ W + b), M x 256 x 256, tile 64x64, BK=32
// ---------------------------------------------------------------------------
__global__ __launch_bounds__(256) void embed_gemm(const float* __restrict__ X,
                                                  const float* __restrict__ W,
                                                  const float* __restrict__ bias,
                                                  float* __restrict__ E) {
  __shared__ __align__(16) float As[64][36];  // padded: rows 16B-aligned, banks spread
  __shared__ __align__(16) float Bs[32][64];
  const int bm = blockIdx.x * 64;
  const int bn = blockIdx.y * 64;
  const int t  = threadIdx.x;
  const int tx = t & 15, ty = t >> 4;
  float acc[4][4] = {};

  for (int k0 = 0; k0 < 256; k0 += 32) {
    // A tile 64x32 (8 floats per thread)
    {
      const int row = t >> 3, seg = t & 7;
#pragma unroll
      for (int half = 0; half < 2; ++half) {
        const int r = row + 32 * half;
        const float4 a = *reinterpret_cast<const float4*>(
            X + (size_t)(bm + r) * DIN + k0 + seg * 4);
        As[r][seg * 4 + 0] = a.x; As[r][seg * 4 + 1] = a.y;
        As[r][seg * 4 + 2] = a.z; As[r][seg * 4 + 3] = a.w;
      }
    }
    // B tile 32x64
    {
      const int row = t >> 4, seg = t & 15;
#pragma unroll
      for (int half = 0; half < 2; ++half) {
        const int r = row + 16 * half;
        const float4 b = *reinterpret_cast<const float4*>(
            W + (size_t)(k0 + r) * HH + bn + seg * 4);
        *reinterpret_cast<float4*>(&Bs[r][seg * 4]) = b;
      }
    }
    __syncthreads();
#pragma unroll
    for (int kk0 = 0; kk0 < 32; kk0 += 4) {
      const float4 b0 = *reinterpret_cast<const float4*>(&Bs[kk0 + 0][tx * 4]);
      const float4 b1 = *reinterpret_cast<const float4*>(&Bs[kk0 + 1][tx * 4]);
      const float4 b2 = *reinterpret_cast<const float4*>(&Bs[kk0 + 2][tx * 4]);
      const float4 b3 = *reinterpret_cast<const float4*>(&Bs[kk0 + 3][tx * 4]);
#pragma unroll
      for (int i = 0; i < 4; ++i) {
        const float4 a = *reinterpret_cast<const float4*>(&As[ty * 4 + i][kk0]);
        acc[i][0] += a.x * b0.x + a.y * b1.x + a.z * b2.x + a.w * b3.x;
        acc[i][1] += a.x * b0.y + a.y * b1.y + a.z * b2.y + a.w * b3.y;
        acc[i][2] += a.x * b0.z + a.y * b1.z + a.z * b2.z + a.w * b3.z;
        acc[i][3] += a.x * b0.w + a.y * b1.w + a.z * b2.w + a.w * b3.w;
      }
    }
    __syncthreads();
  }
  const float4 bb = *reinterpret_cast<const float4*>(bias + bn + tx * 4);
#pragma unroll
  for (int i = 0; i < 4; ++i) {
    float4 o;
    o.x = fmaxf(acc[i][0] + bb.x, 0.f);
    o.y = fmaxf(acc[i][1] + bb.y, 0.f);
    o.z = fmaxf(acc[i][2] + bb.z, 0.f);
    o.w = fmaxf(acc[i][3] + bb.w, 0.f);
    *reinterpret_cast<float4*>(E + (size_t)(bm + ty * 4 + i) * HH + bn + tx * 4) = o;
  }
}

// ---------------------------------------------------------------------------
// l_time: sum over types of weighted squared temporal diffs (block partials)
// ---------------------------------------------------------------------------
__global__ __launch_bounds__(256) void ltime_kernel(const float* __restrict__ ep,
                                                    const float* __restrict__ ea,
                                                    const float* __restrict__ ev,
                                                    float* __restrict__ partials) {
  const unsigned c0 = 7u * NP * HH;      // 28,672,000
  const unsigned c1 = 2u * c0;
  const unsigned c2 = c1 + 7u * NV * HH; // + 358,400
  const float wgt_big   = 1.f / (3.f * 7.f * (float)NP);
  const float wgt_small = 1.f / (3.f * 7.f * (float)NV);
  float local = 0.f;
  for (unsigned i = blockIdx.x * 256u + threadIdx.x; i < c2; i += gridDim.x * 256u) {
    float d, wgt;
    if (i < c1) {
      const float* e = (i < c0) ? ep : ea;
      const unsigned off = (i < c0) ? i : i - c0;
      d = e[off + NP * HH] - e[off];
      wgt = wgt_big;
    } else {
      const unsigned off = i - c1;
      d = ev[off + NV * HH] - ev[off];
      wgt = wgt_small;
    }
    local += wgt * d * d;
  }
  __shared__ float red[256];
  red[threadIdx.x] = local;
  __syncthreads();
  for (int s = 128; s > 0; s >>= 1) {
    if (threadIdx.x < s) red[threadIdx.x] += red[threadIdx.x + s];
    __syncthreads();
  }
  if (threadIdx.x == 0) partials[blockIdx.x] = red[0];
}

// ---------------------------------------------------------------------------
// v_all[t,n,:] = w0*mean(emb_a[t, aidx[n,0..3]]) + w1*emb_v[t,vidx[n]] + w2*emb_p[t,n]
// one block per n, loop t=0..6
// ---------------------------------------------------------------------------
__global__ __launch_bounds__(256) void vall_kernel(const float* __restrict__ ep,
                                                   const float* __restrict__ ea,
                                                   const float* __restrict__ ev,
                                                   const int* __restrict__ aidx,
                                                   const int* __restrict__ vidx,
                                                   const float* __restrict__ wm,
                                                   float* __restrict__ vall) {
  const int n = blockIdx.x;
  const int j = threadIdx.x;
  float w0 = wm[0], w1 = wm[1], w2 = wm[2];
  const float mx = fmaxf(w0, fmaxf(w1, w2));
  const float e0 = expf(w0 - mx), e1 = expf(w1 - mx), e2 = expf(w2 - mx);
  const float inv = 1.f / (e0 + e1 + e2);
  w0 = e0 * inv; w1 = e1 * inv; w2 = e2 * inv;
  const int a0 = aidx[n * 4 + 0], a1 = aidx[n * 4 + 1];
  const int a2 = aidx[n * 4 + 2], a3 = aidx[n * 4 + 3];
  const int vn = vidx[n];
  for (int t = 0; t < 7; ++t) {
    const size_t tb = (size_t)t * NP * HH;
    const float am = 0.25f * (ea[tb + (size_t)a0 * HH + j] + ea[tb + (size_t)a1 * HH + j] +
                              ea[tb + (size_t)a2 * HH + j] + ea[tb + (size_t)a3 * HH + j]);
    const float vv = ev[(size_t)t * NV * HH + (size_t)vn * HH + j];
    const float pp = ep[tb + (size_t)n * HH + j];
    vall[tb + (size_t)n * HH + j] = w0 * am + w1 * vv + w2 * pp;
  }
}

// ---------------------------------------------------------------------------
// GRU: 16 rows per 256-thread block, h in LDS, 5 sequential steps.
// thread j owns output column j; per step computes a_r,a_z,xn,hn for 16 rows.
// ---------------------------------------------------------------------------
__global__ __launch_bounds__(256) void gru_kernel(const float* __restrict__ vall,
                                                  const float* __restrict__ Wx,
                                                  const float* __restrict__ Wh,
                                                  const float* __restrict__ bg,
                                                  float* __restrict__ Hout) {
  __shared__ __align__(16) float xs[16][256];
  __shared__ __align__(16) float hs[16][256];
  const int b0 = blockIdx.x * 16;   // NP % 16 == 0 -> whole block shares g
  const int g  = b0 / NP;
  const int n0 = b0 % NP;
  const int j  = threadIdx.x;
#pragma unroll
  for (int r = 0; r < 16; ++r) hs[r][j] = 0.f;
  const float bjr = bg[j], bjz = bg[j + 256], bjn = bg[j + 512];

  for (int l = 0; l < 5; ++l) {
    __syncthreads();  // prior-step reads of xs/hs complete
    const int tt = 4 + g - l;  // year-1-l, in [0,6]
    const float4* src = reinterpret_cast<const float4*>(vall + ((size_t)tt * NP + n0) * HH);
    float4* dst = reinterpret_cast<float4*>(&xs[0][0]);
#pragma unroll
    for (int q = 0; q < 4; ++q) dst[q * 256 + j] = src[q * 256 + j];
    __syncthreads();

    float ar[16], az[16], xn[16], hn[16];
#pragma unroll
    for (int r = 0; r < 16; ++r) { ar[r] = bjr; az[r] = bjz; xn[r] = bjn; hn[r] = 0.f; }

    for (int k = 0; k < 256; k += 4) {
      float wxr[4], wxz[4], wxn[4], whr[4], whz[4], whn[4];
#pragma unroll
      for (int q = 0; q < 4; ++q) {
        const float* xrow = Wx + (size_t)(k + q) * 768;
        const float* hrow = Wh + (size_t)(k + q) * 768;
        wxr[q] = xrow[j]; wxz[q] = xrow[j + 256]; wxn[q] = xrow[j + 512];
        whr[q] = hrow[j]; whz[q] = hrow[j + 256]; whn[q] = hrow[j + 512];
      }
#pragma unroll
      for (int r = 0; r < 16; ++r) {
        const float4 xv = *reinterpret_cast<const float4*>(&xs[r][k]);
        const float4 hv = *reinterpret_cast<const float4*>(&hs[r][k]);
        ar[r] += xv.x * wxr[0] + xv.y * wxr[1] + xv.z * wxr[2] + xv.w * wxr[3];
        ar[r] += hv.x * whr[0] + hv.y * whr[1] + hv.z * whr[2] + hv.w * whr[3];
        az[r] += xv.x * wxz[0] + xv.y * wxz[1] + xv.z * wxz[2] + xv.w * wxz[3];
        az[r] += hv.x * whz[0] + hv.y * whz[1] + hv.z * whz[2] + hv.w * whz[3];
        xn[r] += xv.x * wxn[0] + xv.y * wxn[1] + xv.z * wxn[2] + xv.w * wxn[3];
        hn[r] += hv.x * whn[0] + hv.y * whn[1] + hv.z * whn[2] + hv.w * whn[3];
      }
    }
    __syncthreads();  // all hs reads done before update
#pragma unroll
    for (int r = 0; r < 16; ++r) {
      const float rg = 1.f / (1.f + expf(-ar[r]));
      const float zg = 1.f / (1.f + expf(-az[r]));
      const float ng = tanhf(xn[r] + rg * hn[r]);
      hs[r][j] = (1.f - zg) * ng + zg * hs[r][j];
    }
  }
  __syncthreads();
#pragma unroll
  for (int r = 0; r < 16; ++r) Hout[(size_t)(b0 + r) * HH + j] = hs[r][j];
}

// ---------------------------------------------------------------------------
// Survival head + per-row loss; one wave per row, 4 rows per block
// ---------------------------------------------------------------------------
__device__ inline float softplusf(float x) { return x > 20.f ? x : log1pf(expf(x)); }

__global__ __launch_bounds__(256) void head_kernel(const float* __restrict__ Hbuf,
                                                   const float* __restrict__ We, const float* __restrict__ be,
                                                   const float* __restrict__ Wm, const float* __restrict__ bmu,
                                                   const float* __restrict__ Ws, const float* __restrict__ bsg,
                                                   const float* __restrict__ yt,
                                                   float* __restrict__ partials) {
  const int wave = threadIdx.x >> 6, lane = threadIdx.x & 63;
  const int b = blockIdx.x * 4 + wave;
  const float* hrow = Hbuf + (size_t)b * HH;
  float pe = 0.f, pm = 0.f, ps = 0.f;
#pragma unroll
  for (int c = 0; c < 4; ++c) {
    const int k = lane + 64 * c;
    const float hv = hrow[k];
    pe += hv * We[k]; pm += hv * Wm[k]; ps += hv * Ws[k];
  }
#pragma unroll
  for (int s = 32; s > 0; s >>= 1) {
    pe += __shfl_down(pe, s);
    pm += __shfl_down(pm, s);
    ps += __shfl_down(ps, s);
  }
  __shared__ float red[4];
  if (lane == 0) {
    const float eta = softplusf(pe + be[0]);
    const float mu  = pm + bmu[0];
    const float sg  = softplusf(ps + bsg[0]) + 0.001f;
    const float inv = 1.f / (sg * 1.41421356237309515f);
    float prev = 0.f, loss = 0.f;
#pragma unroll
    for (int l = 1; l <= 5; ++l) {
      const float z  = (logf((float)l) - mu) * inv;
      const float yc = eta * 0.5f * (1.f + erff(z));
      const float yh = yc - prev; prev = yc;
      const float d  = log1pf(yt[(size_t)b * 5 + (l - 1)] + 1.0f) - log1pf(yh);
      loss += d * d;
    }
    red[wave] = loss;
  }
  __syncthreads();
  if (threadIdx.x == 0) partials[blockIdx.x] = red[0] + red[1] + red[2] + red[3];
}

// ---------------------------------------------------------------------------
// Final: out = lpred_sum / (B*L) + BETA * ltime_sum
// ---------------------------------------------------------------------------
__global__ __launch_bounds__(256) void final_kernel(const float* __restrict__ lt,
                                                    const float* __restrict__ lp,
                                                    float* __restrict__ out) {
  __shared__ float r1[256], r2[256];
  float s1 = 0.f, s2 = 0.f;
  for (int i = threadIdx.x; i < 1024; i += 256) s1 += lt[i];
  for (int i = threadIdx.x; i < 12000; i += 256) s2 += lp[i];
  r1[threadIdx.x] = s1; r2[threadIdx.x] = s2;
  __syncthreads();
  for (int s = 128; s > 0; s >>= 1) {
    if (threadIdx.x < s) { r1[threadIdx.x] += r1[threadIdx.x + s]; r2[threadIdx.x] += r2[threadIdx.x + s]; }
    __syncthreads();
  }
  if (threadIdx.x == 0) out[0] = r2[0] / 240000.f + 0.5f * r1[0];
}

// ---------------------------------------------------------------------------
extern "C" void kernel_launch(void* const* d_in, const int* in_sizes, int n_in,
                              void* d_out, int out_size, void* d_ws, size_t ws_size,
                              hipStream_t stream) {
  (void)in_sizes; (void)n_in; (void)out_size;
  const float* x_paper  = (const float*)d_in[0];
  const float* x_author = (const float*)d_in[1];
  const float* x_venue  = (const float*)d_in[2];
  const int*   aidx     = (const int*)d_in[3];
  const int*   vidx     = (const int*)d_in[4];
  const float* y_true   = (const float*)d_in[5];
  const float* W_paper  = (const float*)d_in[6];
  const float* b_paper  = (const float*)d_in[7];
  const float* W_author = (const float*)d_in[8];
  const float* b_author = (const float*)d_in[9];
  const float* W_venue  = (const float*)d_in[10];
  const float* b_venue  = (const float*)d_in[11];
  const float* w_meta   = (const float*)d_in[12];
  const float* Wx       = (const float*)d_in[13];
  const float* Wh       = (const float*)d_in[14];
  const float* b_gru    = (const float*)d_in[15];
  const float* W_eta    = (const float*)d_in[16];
  const float* b_eta    = (const float*)d_in[17];
  const float* W_mu     = (const float*)d_in[18];
  const float* b_mu     = (const float*)d_in[19];
  const float* W_sigma  = (const float*)d_in[20];
  const float* b_sigma  = (const float*)d_in[21];

  // Workspace layout (floats). Total = 106,918,624 floats ~= 408 MiB.
  float* ws    = (float*)d_ws;
  float* emb_p = ws;                               // 8*16000*256 = 32,768,000
  float* emb_a = emb_p + (size_t)TT * NP * HH;     // 32,768,000
  float* emb_v = emb_a + (size_t)TT * NA * HH;     // 8*200*256 = 409,600
  float* vall  = emb_v + (size_t)TT * NV * HH;     // 7*16000*256 = 28,672,000
  float* Hbuf  = vall  + (size_t)7 * NP * HH;      // 48000*256 = 12,288,000
  float* ltp   = Hbuf  + (size_t)BB * HH;          // 1024
  float* lpp   = ltp + 1024;                       // 12000
  (void)ws_size;

  embed_gemm<<<dim3(2000, 4), 256, 0, stream>>>(x_paper,  W_paper,  b_paper,  emb_p);
  embed_gemm<<<dim3(2000, 4), 256, 0, stream>>>(x_author, W_author, b_author, emb_a);
  embed_gemm<<<dim3(25, 4),   256, 0, stream>>>(x_venue,  W_venue,  b_venue,  emb_v);
  ltime_kernel<<<1024, 256, 0, stream>>>(emb_p, emb_a, emb_v, ltp);
  vall_kernel<<<NP, 256, 0, stream>>>(emb_p, emb_a, emb_v, aidx, vidx, w_meta, vall);
  gru_kernel<<<BB / 16, 256, 0, stream>>>(vall, Wx, Wh, b_gru, Hbuf);
  head_kernel<<<BB / 4, 256, 0, stream>>>(Hbuf, W_eta, b_eta, W_mu, b_mu, W_sigma, b_sigma,
                                          y_true, lpp);
  final_kernel<<<1, 256, 0, stream>>>(ltp, lpp, (float*)d_out);
}

// Round 2
// 921.862 us; speedup vs baseline: 5.0683x; 5.0683x over previous
//
#include <hip/hip_runtime.h>
#include <cmath>

#define NP  16000
#define NV  200
#define HH  256

typedef short short8 __attribute__((ext_vector_type(8)));
typedef float f32x4  __attribute__((ext_vector_type(4)));

__device__ __forceinline__ unsigned short f2b(float f) {
  union { float f; unsigned u; } x; x.f = f;
  unsigned r = x.u + 0x7fffu + ((x.u >> 16) & 1u);
  return (unsigned short)(r >> 16);
}
__device__ __forceinline__ float b2f(unsigned short h) {
  union { unsigned u; float f; } x; x.u = ((unsigned)h) << 16;
  return x.f;
}
__device__ __forceinline__ float b2f_lo(unsigned u) {
  union { unsigned v; float f; } x; x.v = u << 16; return x.f;
}
__device__ __forceinline__ float b2f_hi(unsigned u) {
  union { unsigned v; float f; } x; x.v = u & 0xffff0000u; return x.f;
}
__device__ __forceinline__ unsigned pack2(float a, float b) {
  return (unsigned)f2b(a) | ((unsigned)f2b(b) << 16);
}
__device__ __forceinline__ void gld16(const void* g, void* l) {
  __builtin_amdgcn_global_load_lds((const __attribute__((address_space(1))) void*)g,
                                   (__attribute__((address_space(3))) void*)l, 16, 0, 0);
}

// ---------------------------------------------------------------------------
// fp32 -> bf16 elementwise (n4 = count/4)
// ---------------------------------------------------------------------------
__global__ __launch_bounds__(256) void f32_to_b16(const float* __restrict__ in,
                                                  unsigned short* __restrict__ out, int n4) {
  for (int i = blockIdx.x * 256 + threadIdx.x; i < n4; i += gridDim.x * 256) {
    const float4 v = reinterpret_cast<const float4*>(in)[i];
    uint2 o; o.x = pack2(v.x, v.y); o.y = pack2(v.z, v.w);
    reinterpret_cast<uint2*>(out)[i] = o;
  }
}

// W (256x256 fp32, [k][n]) -> Wt bf16 [n][k]
__global__ __launch_bounds__(256) void packWt(const float* __restrict__ W,
                                              unsigned short* __restrict__ Wt) {
  const int n = blockIdx.x, k = threadIdx.x;
  Wt[n * 256 + k] = f2b(W[k * 256 + n]);
}

// Wx (256x768), Wh (256x768) -> W2t bf16 [col 768][k 512] (k<256: Wx, else Wh)
__global__ __launch_bounds__(256) void packW2t(const float* __restrict__ Wx,
                                               const float* __restrict__ Wh,
                                               unsigned short* __restrict__ W2t) {
  const int col = blockIdx.x;
  for (int k = threadIdx.x; k < 512; k += 256)
    W2t[(size_t)col * 512 + k] =
        f2b(k < 256 ? Wx[(size_t)k * 768 + col] : Wh[(size_t)(k - 256) * 768 + col]);
}

// ---------------------------------------------------------------------------
// Embed GEMM bf16 MFMA: E = relu(X @ W + b), tile 128x128, BK=64, K=256
// X [M][256] bf16, Wt [256][256] bf16 ([n][k]), E [M][256] bf16
// ---------------------------------------------------------------------------
__global__ __launch_bounds__(256) void embed_mfma(const unsigned short* __restrict__ X,
                                                  const unsigned short* __restrict__ Wt,
                                                  const float* __restrict__ bias,
                                                  unsigned short* __restrict__ E, int M) {
  __shared__ __align__(16) unsigned short As[128 * 64];
  __shared__ __align__(16) unsigned short Bs[128 * 64];
  const int t = threadIdx.x, w = t >> 6, l = t & 63;
  const int m0 = blockIdx.x * 128, n0 = blockIdx.y * 128;
  const int srow = l >> 3;
  const int scol = ((l & 7) ^ srow) * 8;  // inverse-swizzled global slot
  const f32x4 zero = {0.f, 0.f, 0.f, 0.f};
  f32x4 acc[4][4];
#pragma unroll
  for (int i = 0; i < 4; ++i)
#pragma unroll
    for (int j = 0; j < 4; ++j) acc[i][j] = zero;

  const int mrow0 = 64 * (w >> 1), ncol0 = 64 * (w & 1);
#pragma unroll
  for (int c = 0; c < 4; ++c) {
#pragma unroll
    for (int i = 0; i < 4; ++i) {
      const int seg = 4 * w + i;
      gld16(X + (size_t)(m0 + 8 * seg + srow) * 256 + c * 64 + scol, (void*)(As + seg * 512));
    }
#pragma unroll
    for (int i = 0; i < 4; ++i) {
      const int seg = 4 * w + i;
      gld16(Wt + (size_t)(n0 + 8 * seg + srow) * 256 + c * 64 + scol, (void*)(Bs + seg * 512));
    }
    __syncthreads();
#pragma unroll
    for (int ks = 0; ks < 2; ++ks) {
      short8 av[4], bv[4];
#pragma unroll
      for (int mi = 0; mi < 4; ++mi) {
        const int r = mrow0 + mi * 16 + (l & 15);
        const int slot = (ks * 4 + (l >> 4)) ^ (r & 7);
        av[mi] = *reinterpret_cast<const short8*>(As + r * 64 + slot * 8);
      }
#pragma unroll
      for (int nj = 0; nj < 4; ++nj) {
        const int r = ncol0 + nj * 16 + (l & 15);
        const int slot = (ks * 4 + (l >> 4)) ^ (r & 7);
        bv[nj] = *reinterpret_cast<const short8*>(Bs + r * 64 + slot * 8);
      }
#pragma unroll
      for (int mi = 0; mi < 4; ++mi)
#pragma unroll
        for (int nj = 0; nj < 4; ++nj)
          acc[mi][nj] = __builtin_amdgcn_mfma_f32_16x16x32_bf16(av[mi], bv[nj], acc[mi][nj], 0, 0, 0);
    }
    __syncthreads();
  }
  // epilogue: bias + relu, bf16 store
#pragma unroll
  for (int nj = 0; nj < 4; ++nj) {
    const int colg = n0 + ncol0 + nj * 16 + (l & 15);
    const float bv = bias[colg];
#pragma unroll
    for (int mi = 0; mi < 4; ++mi) {
      const int rbase = m0 + mrow0 + mi * 16 + (l >> 4) * 4;
#pragma unroll
      for (int e = 0; e < 4; ++e) {
        const int row = rbase + e;
        if (row < M) E[(size_t)row * 256 + colg] = f2b(fmaxf(acc[mi][nj][e] + bv, 0.f));
      }
    }
  }
}

// ---------------------------------------------------------------------------
// l_time from bf16 embeddings (oct = 8 bf16 per thread-iter)
// ---------------------------------------------------------------------------
__global__ __launch_bounds__(256) void ltime_kernel(const unsigned short* __restrict__ ep,
                                                    const unsigned short* __restrict__ ea,
                                                    const unsigned short* __restrict__ ev,
                                                    float* __restrict__ partials) {
  const unsigned PO = 3584000u;       // 7*16000*256/8
  const unsigned VO = 44800u;         // 7*200*256/8
  const unsigned TOT = 2u * PO + VO;
  const unsigned SL = 512000u;        // 16000*256/8
  const unsigned SLV = 6400u;         // 200*256/8
  const float wbig = 1.f / (3.f * 7.f * 16000.f);
  const float wsmall = 1.f / (3.f * 7.f * 200.f);
  float local = 0.f;
  for (unsigned i = blockIdx.x * 256u + threadIdx.x; i < TOT; i += gridDim.x * 256u) {
    const unsigned short* base; unsigned off, sl; float wgt;
    if (i < 2u * PO) { base = (i < PO) ? ep : ea; off = (i < PO) ? i : i - PO; sl = SL; wgt = wbig; }
    else             { base = ev; off = i - 2u * PO; sl = SLV; wgt = wsmall; }
    const uint4 u0 = *reinterpret_cast<const uint4*>(base + (size_t)off * 8);
    const uint4 u1 = *reinterpret_cast<const uint4*>(base + (size_t)(off + sl) * 8);
    float s = 0.f, d;
    d = b2f_lo(u1.x) - b2f_lo(u0.x); s += d * d;
    d = b2f_hi(u1.x) - b2f_hi(u0.x); s += d * d;
    d = b2f_lo(u1.y) - b2f_lo(u0.y); s += d * d;
    d = b2f_hi(u1.y) - b2f_hi(u0.y); s += d * d;
    d = b2f_lo(u1.z) - b2f_lo(u0.z); s += d * d;
    d = b2f_hi(u1.z) - b2f_hi(u0.z); s += d * d;
    d = b2f_lo(u1.w) - b2f_lo(u0.w); s += d * d;
    d = b2f_hi(u1.w) - b2f_hi(u0.w); s += d * d;
    local += wgt * s;
  }
  __shared__ float red[256];
  red[threadIdx.x] = local;
  __syncthreads();
  for (int s = 128; s > 0; s >>= 1) {
    if (threadIdx.x < s) red[threadIdx.x] += red[threadIdx.x + s];
    __syncthreads();
  }
  if (threadIdx.x == 0) partials[blockIdx.x] = red[0];
}

// ---------------------------------------------------------------------------
// v_all bf16: wave per n, lane handles 4 cols (uint2)
// ---------------------------------------------------------------------------
__global__ __launch_bounds__(256) void vall_kernel(const unsigned short* __restrict__ ep,
                                                   const unsigned short* __restrict__ ea,
                                                   const unsigned short* __restrict__ ev,
                                                   const int* __restrict__ aidx,
                                                   const int* __restrict__ vidx,
                                                   const float* __restrict__ wm,
                                                   unsigned short* __restrict__ vall) {
  const int w = threadIdx.x >> 6, l = threadIdx.x & 63;
  const int n = blockIdx.x * 4 + w;
  float w0 = wm[0], w1 = wm[1], w2 = wm[2];
  const float mx = fmaxf(w0, fmaxf(w1, w2));
  const float e0 = expf(w0 - mx), e1 = expf(w1 - mx), e2 = expf(w2 - mx);
  const float inv = 1.f / (e0 + e1 + e2);
  w0 = e0 * inv; w1 = e1 * inv; w2 = e2 * inv;
  const int a0 = aidx[n * 4 + 0], a1 = aidx[n * 4 + 1];
  const int a2 = aidx[n * 4 + 2], a3 = aidx[n * 4 + 3];
  const int vn = vidx[n];
  const int cb = l * 4;
  for (int t = 0; t < 7; ++t) {
    const size_t tb = (size_t)t * NP * HH;
    const uint2 ua0 = *reinterpret_cast<const uint2*>(ea + tb + (size_t)a0 * HH + cb);
    const uint2 ua1 = *reinterpret_cast<const uint2*>(ea + tb + (size_t)a1 * HH + cb);
    const uint2 ua2 = *reinterpret_cast<const uint2*>(ea + tb + (size_t)a2 * HH + cb);
    const uint2 ua3 = *reinterpret_cast<const uint2*>(ea + tb + (size_t)a3 * HH + cb);
    const uint2 uv  = *reinterpret_cast<const uint2*>(ev + (size_t)t * NV * HH + (size_t)vn * HH + cb);
    const uint2 up  = *reinterpret_cast<const uint2*>(ep + tb + (size_t)n * HH + cb);
    float o[4];
    o[0] = w0 * 0.25f * (b2f_lo(ua0.x) + b2f_lo(ua1.x) + b2f_lo(ua2.x) + b2f_lo(ua3.x)) + w1 * b2f_lo(uv.x) + w2 * b2f_lo(up.x);
    o[1] = w0 * 0.25f * (b2f_hi(ua0.x) + b2f_hi(ua1.x) + b2f_hi(ua2.x) + b2f_hi(ua3.x)) + w1 * b2f_hi(uv.x) + w2 * b2f_hi(up.x);
    o[2] = w0 * 0.25f * (b2f_lo(ua0.y) + b2f_lo(ua1.y) + b2f_lo(ua2.y) + b2f_lo(ua3.y)) + w1 * b2f_lo(uv.y) + w2 * b2f_lo(up.y);
    o[3] = w0 * 0.25f * (b2f_hi(ua0.y) + b2f_hi(ua1.y) + b2f_hi(ua2.y) + b2f_hi(ua3.y)) + w1 * b2f_hi(uv.y) + w2 * b2f_hi(up.y);
    uint2 ov; ov.x = pack2(o[0], o[1]); ov.y = pack2(o[2], o[3]);
    *reinterpret_cast<uint2*>(vall + tb + (size_t)n * HH + cb) = ov;
  }
}

// ---------------------------------------------------------------------------
// GRU step, bf16 MFMA. Block: 128 rows x (r|z|n)x64 cols, K=512 ([x;h]).
// chunks 0-3: x-part (accR,accZ,accXN); chunks 4-7: h-part (accR,accZ,accHN).
// ---------------------------------------------------------------------------
template <bool FIRST>
__global__ __launch_bounds__(256) void gru_step(const unsigned short* __restrict__ vall16,
                                                const unsigned short* __restrict__ W2t,
                                                const float* __restrict__ bg,
                                                const unsigned short* __restrict__ Hsrc,
                                                unsigned short* __restrict__ Hdst,
                                                int lstep) {
  __shared__ __align__(16) unsigned short As[128 * 64];
  __shared__ __align__(16) unsigned short Bs[192 * 64];
  const int t = threadIdx.x, w = t >> 6, l = t & 63;
  const int bx = blockIdx.x, j0 = blockIdx.y * 64;
  const int g = bx / 125;                 // 125 blocks per year-group
  const int n0 = (bx * 128) % 16000;
  const int tt = 4 + g - lstep;
  const unsigned short* xsrc = vall16 + ((size_t)tt * NP + n0) * 256;
  const unsigned short* hsrc = Hsrc + (size_t)bx * 128 * 256;
  const int srow = l >> 3;
  const int scol = ((l & 7) ^ srow) * 8;
  const f32x4 zero = {0.f, 0.f, 0.f, 0.f};
  f32x4 accR[2][4], accZ[2][4], accXN[2][4], accHN[2][4];
#pragma unroll
  for (int mi = 0; mi < 2; ++mi)
#pragma unroll
    for (int nj = 0; nj < 4; ++nj) {
      accR[mi][nj] = zero; accZ[mi][nj] = zero;
      accXN[mi][nj] = zero; accHN[mi][nj] = zero;
    }

  const int NCH = FIRST ? 4 : 8;
#pragma unroll
  for (int c = 0; c < NCH; ++c) {
    const unsigned short* abase = (c < 4) ? (xsrc + c * 64) : (hsrc + (c - 4) * 64);
#pragma unroll
    for (int i = 0; i < 4; ++i) {
      const int seg = 4 * w + i;
      gld16(abase + (size_t)(8 * seg + srow) * 256 + scol, (void*)(As + seg * 512));
    }
#pragma unroll
    for (int i = 0; i < 6; ++i) {
      const int seg = 6 * w + i;                 // 0..23
      const int gate = seg >> 3, sub = seg & 7;
      const int wrow = gate * 256 + j0 + 8 * sub + srow;
      gld16(W2t + (size_t)wrow * 512 + c * 64 + scol, (void*)(Bs + seg * 512));
    }
    __syncthreads();
#pragma unroll
    for (int ks = 0; ks < 2; ++ks) {
      short8 av[2], bv[12];
#pragma unroll
      for (int mi = 0; mi < 2; ++mi) {
        const int r = 32 * w + mi * 16 + (l & 15);
        const int slot = (ks * 4 + (l >> 4)) ^ (r & 7);
        av[mi] = *reinterpret_cast<const short8*>(As + r * 64 + slot * 8);
      }
#pragma unroll
      for (int q = 0; q < 12; ++q) {             // q = gate*4 + nj
        const int r = (q >> 2) * 64 + (q & 3) * 16 + (l & 15);
        const int slot = (ks * 4 + (l >> 4)) ^ (r & 7);
        bv[q] = *reinterpret_cast<const short8*>(Bs + r * 64 + slot * 8);
      }
#pragma unroll
      for (int mi = 0; mi < 2; ++mi)
#pragma unroll
        for (int nj = 0; nj < 4; ++nj) {
          accR[mi][nj] = __builtin_amdgcn_mfma_f32_16x16x32_bf16(av[mi], bv[nj], accR[mi][nj], 0, 0, 0);
          accZ[mi][nj] = __builtin_amdgcn_mfma_f32_16x16x32_bf16(av[mi], bv[4 + nj], accZ[mi][nj], 0, 0, 0);
          if (c < 4)
            accXN[mi][nj] = __builtin_amdgcn_mfma_f32_16x16x32_bf16(av[mi], bv[8 + nj], accXN[mi][nj], 0, 0, 0);
          else
            accHN[mi][nj] = __builtin_amdgcn_mfma_f32_16x16x32_bf16(av[mi], bv[8 + nj], accHN[mi][nj], 0, 0, 0);
        }
    }
    __syncthreads();
  }
  // epilogue: gates
#pragma unroll
  for (int nj = 0; nj < 4; ++nj) {
    const int j = j0 + nj * 16 + (l & 15);
    const float br = bg[j], bz = bg[256 + j], bn = bg[512 + j];
#pragma unroll
    for (int mi = 0; mi < 2; ++mi) {
      const int rbase = bx * 128 + 32 * w + mi * 16 + (l >> 4) * 4;
#pragma unroll
      for (int e = 0; e < 4; ++e) {
        const size_t idx = (size_t)(rbase + e) * 256 + j;
        const float rg = 1.f / (1.f + expf(-(accR[mi][nj][e] + br)));
        const float zg = 1.f / (1.f + expf(-(accZ[mi][nj][e] + bz)));
        const float hn = FIRST ? 0.f : accHN[mi][nj][e];
        const float ng = tanhf(accXN[mi][nj][e] + bn + rg * hn);
        const float hold = FIRST ? 0.f : b2f(Hsrc[idx]);
        Hdst[idx] = f2b((1.f - zg) * ng + zg * hold);
      }
    }
  }
}

// ---------------------------------------------------------------------------
// Survival head + per-row loss (H in bf16)
// ---------------------------------------------------------------------------
__device__ inline float softplusf(float x) { return x > 20.f ? x : log1pf(expf(x)); }

__global__ __launch_bounds__(256) void head_kernel(const unsigned short* __restrict__ Hbuf,
                                                   const float* __restrict__ We, const float* __restrict__ be,
                                                   const float* __restrict__ Wm, const float* __restrict__ bmu,
                                                   const float* __restrict__ Ws, const float* __restrict__ bsg,
                                                   const float* __restrict__ yt,
                                                   float* __restrict__ partials) {
  const int wave = threadIdx.x >> 6, lane = threadIdx.x & 63;
  const int b = blockIdx.x * 4 + wave;
  const unsigned short* hrow = Hbuf + (size_t)b * HH;
  float pe = 0.f, pm = 0.f, ps = 0.f;
#pragma unroll
  for (int c = 0; c < 4; ++c) {
    const int k = lane + 64 * c;
    const float hv = b2f(hrow[k]);
    pe += hv * We[k]; pm += hv * Wm[k]; ps += hv * Ws[k];
  }
#pragma unroll
  for (int s = 32; s > 0; s >>= 1) {
    pe += __shfl_down(pe, s);
    pm += __shfl_down(pm, s);
    ps += __shfl_down(ps, s);
  }
  __shared__ float red[4];
  if (lane == 0) {
    const float eta = softplusf(pe + be[0]);
    const float mu  = pm + bmu[0];
    const float sg  = softplusf(ps + bsg[0]) + 0.001f;
    const float inv = 1.f / (sg * 1.41421356237309515f);
    float prev = 0.f, loss = 0.f;
#pragma unroll
    for (int h = 1; h <= 5; ++h) {
      const float z  = (logf((float)h) - mu) * inv;
      const float yc = eta * 0.5f * (1.f + erff(z));
      const float yh = yc - prev; prev = yc;
      const float d  = log1pf(yt[(size_t)b * 5 + (h - 1)] + 1.0f) - log1pf(yh);
      loss += d * d;
    }
    red[wave] = loss;
  }
  __syncthreads();
  if (threadIdx.x == 0) partials[blockIdx.x] = red[0] + red[1] + red[2] + red[3];
}

__global__ __launch_bounds__(256) void final_kernel(const float* __restrict__ lt,
                                                    const float* __restrict__ lp,
                                                    float* __restrict__ out) {
  __shared__ float r1[256], r2[256];
  float s1 = 0.f, s2 = 0.f;
  for (int i = threadIdx.x; i < 1024; i += 256) s1 += lt[i];
  for (int i = threadIdx.x; i < 12000; i += 256) s2 += lp[i];
  r1[threadIdx.x] = s1; r2[threadIdx.x] = s2;
  __syncthreads();
  for (int s = 128; s > 0; s >>= 1) {
    if (threadIdx.x < s) { r1[threadIdx.x] += r1[threadIdx.x + s]; r2[threadIdx.x] += r2[threadIdx.x + s]; }
    __syncthreads();
  }
  if (threadIdx.x == 0) out[0] = r2[0] / 240000.f + 0.5f * r1[0];
}

// ---------------------------------------------------------------------------
extern "C" void kernel_launch(void* const* d_in, const int* in_sizes, int n_in,
                              void* d_out, int out_size, void* d_ws, size_t ws_size,
                              hipStream_t stream) {
  (void)in_sizes; (void)n_in; (void)out_size; (void)ws_size;
  const float* x_paper  = (const float*)d_in[0];
  const float* x_author = (const float*)d_in[1];
  const float* x_venue  = (const float*)d_in[2];
  const int*   aidx     = (const int*)d_in[3];
  const int*   vidx     = (const int*)d_in[4];
  const float* y_true   = (const float*)d_in[5];
  const float* W_paper  = (const float*)d_in[6];
  const float* b_paper  = (const float*)d_in[7];
  const float* W_author = (const float*)d_in[8];
  const float* b_author = (const float*)d_in[9];
  const float* W_venue  = (const float*)d_in[10];
  const float* b_venue  = (const float*)d_in[11];
  const float* w_meta   = (const float*)d_in[12];
  const float* Wx       = (const float*)d_in[13];
  const float* Wh       = (const float*)d_in[14];
  const float* b_gru    = (const float*)d_in[15];
  const float* W_eta    = (const float*)d_in[16];
  const float* b_eta    = (const float*)d_in[17];
  const float* W_mu     = (const float*)d_in[18];
  const float* b_mu     = (const float*)d_in[19];
  const float* W_sigma  = (const float*)d_in[20];
  const float* b_sigma  = (const float*)d_in[21];

  // ws layout (bf16 shorts unless noted)
  unsigned short* p = (unsigned short*)d_ws;
  unsigned short* xp16 = p;                 p += (size_t)8 * NP * 256;   // 32.768M
  unsigned short* xa16 = p;                 p += (size_t)8 * NP * 256;
  unsigned short* xv16 = p;                 p += (size_t)8 * NV * 256;   // 409600
  unsigned short* ep16 = p;                 p += (size_t)8 * NP * 256;   // (follows xv16: venue over-read slack)
  unsigned short* ea16 = p;                 p += (size_t)8 * NP * 256;
  unsigned short* ev16 = p;                 p += (size_t)8 * NV * 256;
  unsigned short* va16 = p;                 p += (size_t)7 * NP * 256;   // 28.672M
  unsigned short* Hb0  = p;                 p += (size_t)48000 * 256;
  unsigned short* Hb1  = p;                 p += (size_t)48000 * 256;
  unsigned short* Wtp  = p;                 p += 256 * 256;
  unsigned short* Wta  = p;                 p += 256 * 256;
  unsigned short* Wtv  = p;                 p += 256 * 256;
  unsigned short* W2t  = p;                 p += (size_t)768 * 512;
  float* ltp = (float*)p;
  float* lpp = ltp + 1024;

  // converts + packs
  f32_to_b16<<<2048, 256, 0, stream>>>(x_paper,  xp16, 8 * NP * 256 / 4);
  f32_to_b16<<<2048, 256, 0, stream>>>(x_author, xa16, 8 * NP * 256 / 4);
  f32_to_b16<<<400,  256, 0, stream>>>(x_venue,  xv16, 8 * NV * 256 / 4);
  packWt<<<256, 256, 0, stream>>>(W_paper,  Wtp);
  packWt<<<256, 256, 0, stream>>>(W_author, Wta);
  packWt<<<256, 256, 0, stream>>>(W_venue,  Wtv);
  packW2t<<<768, 256, 0, stream>>>(Wx, Wh, W2t);

  // embeddings
  embed_mfma<<<dim3(1000, 2), 256, 0, stream>>>(xp16, Wtp, b_paper,  ep16, 8 * NP);
  embed_mfma<<<dim3(1000, 2), 256, 0, stream>>>(xa16, Wta, b_author, ea16, 8 * NP);
  embed_mfma<<<dim3(13, 2),   256, 0, stream>>>(xv16, Wtv, b_venue,  ev16, 8 * NV);

  ltime_kernel<<<1024, 256, 0, stream>>>(ep16, ea16, ev16, ltp);
  vall_kernel<<<NP / 4, 256, 0, stream>>>(ep16, ea16, ev16, aidx, vidx, w_meta, va16);

  // GRU: ping-pong H; step l reads Hb[(l+1)&1], writes Hb[l&1]
  gru_step<true><<<dim3(375, 4), 256, 0, stream>>>(va16, W2t, b_gru, Hb0, Hb0, 0);
  gru_step<false><<<dim3(375, 4), 256, 0, stream>>>(va16, W2t, b_gru, Hb0, Hb1, 1);
  gru_step<false><<<dim3(375, 4), 256, 0, stream>>>(va16, W2t, b_gru, Hb1, Hb0, 2);
  gru_step<false><<<dim3(375, 4), 256, 0, stream>>>(va16, W2t, b_gru, Hb0, Hb1, 3);
  gru_step<false><<<dim3(375, 4), 256, 0, stream>>>(va16, W2t, b_gru, Hb1, Hb0, 4);

  head_kernel<<<12000, 256, 0, stream>>>(Hb0, W_eta, b_eta, W_mu, b_mu, W_sigma, b_sigma,
                                         y_true, lpp);
  final_kernel<<<1, 256, 0, stream>>>(ltp, lpp, (float*)d_out);
}

// Round 3
// 709.584 us; speedup vs baseline: 6.5845x; 1.2992x over previous
//
#include <hip/hip_runtime.h>
#include <cmath>

#define NP  16000
#define NV  200
#define HH  256

typedef short short8 __attribute__((ext_vector_type(8)));
typedef float f32x4  __attribute__((ext_vector_type(4)));

__device__ __forceinline__ unsigned short f2b(float f) {
  union { float f; unsigned u; } x; x.f = f;
  unsigned r = x.u + 0x7fffu + ((x.u >> 16) & 1u);
  return (unsigned short)(r >> 16);
}
__device__ __forceinline__ float b2f(unsigned short h) {
  union { unsigned u; float f; } x; x.u = ((unsigned)h) << 16;
  return x.f;
}
__device__ __forceinline__ float b2f_lo(unsigned u) {
  union { unsigned v; float f; } x; x.v = u << 16; return x.f;
}
__device__ __forceinline__ float b2f_hi(unsigned u) {
  union { unsigned v; float f; } x; x.v = u & 0xffff0000u; return x.f;
}
// pack 2 f32 -> 2 bf16 (RNE) in one instr
__device__ __forceinline__ unsigned cvt2(float a, float b) {
  unsigned r;
  asm("v_cvt_pk_bf16_f32 %0, %1, %2" : "=v"(r) : "v"(a), "v"(b));
  return r;
}
__device__ __forceinline__ void gld16(const void* g, void* l) {
  __builtin_amdgcn_global_load_lds((const __attribute__((address_space(1))) void*)g,
                                   (__attribute__((address_space(3))) void*)l, 16, 0, 0);
}
__device__ __forceinline__ float sigm(float x) { return 1.f / (1.f + __expf(-x)); }
__device__ __forceinline__ float tanhfast(float x) {
  const float e = __expf(-2.f * fabsf(x));
  const float t = (1.f - e) / (1.f + e);
  return x < 0.f ? -t : t;
}
// bijective chunked XCD swizzle (m204): orig -> work, nwg = 8q + r
__device__ __forceinline__ int xcd_swz(int orig, int q, int r) {
  const int xcd = orig & 7, loc = orig >> 3;
  return (xcd < r ? xcd * (q + 1) : r * (q + 1) + (xcd - r) * q) + loc;
}

// ---------------------------------------------------------------------------
// Weight packs
// W (256x256 fp32, [k][n]) -> Wt bf16 [n][k]
__global__ __launch_bounds__(256) void packWt(const float* __restrict__ W,
                                              unsigned short* __restrict__ Wt) {
  const int n = blockIdx.x, k = threadIdx.x;
  Wt[n * 256 + k] = f2b(W[k * 256 + n]);
}
// Wx (256x768), Wh (256x768) -> W2t bf16 [col 768][k 512] (k<256: Wx, else Wh)
__global__ __launch_bounds__(256) void packW2t(const float* __restrict__ Wx,
                                               const float* __restrict__ Wh,
                                               unsigned short* __restrict__ W2t) {
  const int col = blockIdx.x;
  for (int k = threadIdx.x; k < 512; k += 256)
    W2t[(size_t)col * 512 + k] =
        f2b(k < 256 ? Wx[(size_t)k * 768 + col] : Wh[(size_t)(k - 256) * 768 + col]);
}

// ---------------------------------------------------------------------------
// Embed GEMM: E = relu(Xf32 @ W + b), tile 128x128, BK=64, K=256.
// A reg-staged fp32->bf16 into swizzled LDS; B gld16 (pre-swizzled source).
// 1D swizzled grid: work>>1 = m-tile, work&1 = n-block.
// ---------------------------------------------------------------------------
__global__ __launch_bounds__(256) void embed_f32(const float* __restrict__ Xf,
                                                 const unsigned short* __restrict__ Wt,
                                                 const float* __restrict__ bias,
                                                 unsigned short* __restrict__ E,
                                                 int M, int swq, int swr) {
  __shared__ __align__(16) unsigned short As[128 * 64];
  __shared__ __align__(16) unsigned short Bs[128 * 64];
  const int t = threadIdx.x, w = t >> 6, l = t & 63;
  const int work = xcd_swz(blockIdx.x, swq, swr);
  const int m0 = (work >> 1) * 128, n0 = (work & 1) * 128;
  const int srow = l >> 3;
  const int scol = ((l & 7) ^ srow) * 8;
  const f32x4 zero = {0.f, 0.f, 0.f, 0.f};
  f32x4 acc[4][4];
#pragma unroll
  for (int i = 0; i < 4; ++i)
#pragma unroll
    for (int j = 0; j < 4; ++j) acc[i][j] = zero;
  const int mrow0 = 64 * (w >> 1), ncol0 = 64 * (w & 1);

#pragma unroll
  for (int c = 0; c < 4; ++c) {
    // A: reg-stage 128x64 fp32 -> bf16 swizzled LDS
#pragma unroll
    for (int a = 0; a < 2; ++a) {
      const int idx = t * 2 + a;            // 0..511
      const int row = idx >> 2, cg = idx & 3;
      const int grow = min(m0 + row, M - 1);
      const float4* s = reinterpret_cast<const float4*>(Xf + (size_t)grow * 256 + c * 64 + cg * 16);
      const float4 f0 = s[0], f1 = s[1], f2 = s[2], f3 = s[3];
      uint4 u0, u1;
      u0.x = cvt2(f0.x, f0.y); u0.y = cvt2(f0.z, f0.w);
      u0.z = cvt2(f1.x, f1.y); u0.w = cvt2(f1.z, f1.w);
      u1.x = cvt2(f2.x, f2.y); u1.y = cvt2(f2.z, f2.w);
      u1.z = cvt2(f3.x, f3.y); u1.w = cvt2(f3.z, f3.w);
      const int s0 = (cg * 2) ^ (row & 7), s1 = (cg * 2 + 1) ^ (row & 7);
      *reinterpret_cast<uint4*>(As + row * 64 + s0 * 8) = u0;
      *reinterpret_cast<uint4*>(As + row * 64 + s1 * 8) = u1;
    }
    // B: gld16, pre-swizzled source
#pragma unroll
    for (int i = 0; i < 4; ++i) {
      const int seg = 4 * w + i;
      gld16(Wt + (size_t)(n0 + 8 * seg + srow) * 256 + c * 64 + scol, (void*)(Bs + seg * 512));
    }
    __syncthreads();
#pragma unroll
    for (int ks = 0; ks < 2; ++ks) {
      short8 av[4], bv[4];
#pragma unroll
      for (int mi = 0; mi < 4; ++mi) {
        const int r = mrow0 + mi * 16 + (l & 15);
        const int slot = (ks * 4 + (l >> 4)) ^ (r & 7);
        av[mi] = *reinterpret_cast<const short8*>(As + r * 64 + slot * 8);
      }
#pragma unroll
      for (int nj = 0; nj < 4; ++nj) {
        const int r = ncol0 + nj * 16 + (l & 15);
        const int slot = (ks * 4 + (l >> 4)) ^ (r & 7);
        bv[nj] = *reinterpret_cast<const short8*>(Bs + r * 64 + slot * 8);
      }
#pragma unroll
      for (int mi = 0; mi < 4; ++mi)
#pragma unroll
        for (int nj = 0; nj < 4; ++nj)
          acc[mi][nj] = __builtin_amdgcn_mfma_f32_16x16x32_bf16(av[mi], bv[nj], acc[mi][nj], 0, 0, 0);
    }
    __syncthreads();
  }
#pragma unroll
  for (int nj = 0; nj < 4; ++nj) {
    const int colg = n0 + ncol0 + nj * 16 + (l & 15);
    const float bv = bias[colg];
#pragma unroll
    for (int mi = 0; mi < 4; ++mi) {
      const int rbase = m0 + mrow0 + mi * 16 + (l >> 4) * 4;
#pragma unroll
      for (int e = 0; e < 4; ++e) {
        const int row = rbase + e;
        if (row < M) E[(size_t)row * 256 + colg] = f2b(fmaxf(acc[mi][nj][e] + bv, 0.f));
      }
    }
  }
}

// ---------------------------------------------------------------------------
// GX GEMM: GX = vall @ Wx + b_gru  (M=112000, N=768, K=256), bf16 out.
// A bf16 gld16; B = W2t k-cols [0,256), row stride 512.
// 1D swizzled grid 5250: work/6 = m-tile, work%6 = n-block.
// ---------------------------------------------------------------------------
__global__ __launch_bounds__(256) void gx_gemm(const unsigned short* __restrict__ Abf,
                                               const unsigned short* __restrict__ W2t,
                                               const float* __restrict__ bias,
                                               unsigned short* __restrict__ GX) {
  __shared__ __align__(16) unsigned short As[128 * 64];
  __shared__ __align__(16) unsigned short Bs[128 * 64];
  const int t = threadIdx.x, w = t >> 6, l = t & 63;
  const int work = xcd_swz(blockIdx.x, 656, 2);
  const int m0 = (work / 6) * 128, n0 = (work % 6) * 128;
  const int srow = l >> 3;
  const int scol = ((l & 7) ^ srow) * 8;
  const f32x4 zero = {0.f, 0.f, 0.f, 0.f};
  f32x4 acc[4][4];
#pragma unroll
  for (int i = 0; i < 4; ++i)
#pragma unroll
    for (int j = 0; j < 4; ++j) acc[i][j] = zero;
  const int mrow0 = 64 * (w >> 1), ncol0 = 64 * (w & 1);

#pragma unroll
  for (int c = 0; c < 4; ++c) {
#pragma unroll
    for (int i = 0; i < 4; ++i) {
      const int seg = 4 * w + i;
      gld16(Abf + (size_t)(m0 + 8 * seg + srow) * 256 + c * 64 + scol, (void*)(As + seg * 512));
    }
#pragma unroll
    for (int i = 0; i < 4; ++i) {
      const int seg = 4 * w + i;
      gld16(W2t + (size_t)(n0 + 8 * seg + srow) * 512 + c * 64 + scol, (void*)(Bs + seg * 512));
    }
    __syncthreads();
#pragma unroll
    for (int ks = 0; ks < 2; ++ks) {
      short8 av[4], bv[4];
#pragma unroll
      for (int mi = 0; mi < 4; ++mi) {
        const int r = mrow0 + mi * 16 + (l & 15);
        const int slot = (ks * 4 + (l >> 4)) ^ (r & 7);
        av[mi] = *reinterpret_cast<const short8*>(As + r * 64 + slot * 8);
      }
#pragma unroll
      for (int nj = 0; nj < 4; ++nj) {
        const int r = ncol0 + nj * 16 + (l & 15);
        const int slot = (ks * 4 + (l >> 4)) ^ (r & 7);
        bv[nj] = *reinterpret_cast<const short8*>(Bs + r * 64 + slot * 8);
      }
#pragma unroll
      for (int mi = 0; mi < 4; ++mi)
#pragma unroll
        for (int nj = 0; nj < 4; ++nj)
          acc[mi][nj] = __builtin_amdgcn_mfma_f32_16x16x32_bf16(av[mi], bv[nj], acc[mi][nj], 0, 0, 0);
    }
    __syncthreads();
  }
#pragma unroll
  for (int nj = 0; nj < 4; ++nj) {
    const int colg = n0 + ncol0 + nj * 16 + (l & 15);
    const float bv = bias[colg];
#pragma unroll
    for (int mi = 0; mi < 4; ++mi) {
      const int rbase = m0 + mrow0 + mi * 16 + (l >> 4) * 4;
#pragma unroll
      for (int e = 0; e < 4; ++e)
        GX[(size_t)(rbase + e) * 768 + colg] = f2b(acc[mi][nj][e] + bv);
    }
  }
}

// ---------------------------------------------------------------------------
// l_time from bf16 embeddings
// ---------------------------------------------------------------------------
__global__ __launch_bounds__(256) void ltime_kernel(const unsigned short* __restrict__ ep,
                                                    const unsigned short* __restrict__ ea,
                                                    const unsigned short* __restrict__ ev,
                                                    float* __restrict__ partials) {
  const unsigned PO = 3584000u, VO = 44800u;
  const unsigned TOT = 2u * PO + VO;
  const unsigned SL = 512000u, SLV = 6400u;
  const float wbig = 1.f / (3.f * 7.f * 16000.f);
  const float wsmall = 1.f / (3.f * 7.f * 200.f);
  float local = 0.f;
  for (unsigned i = blockIdx.x * 256u + threadIdx.x; i < TOT; i += gridDim.x * 256u) {
    const unsigned short* base; unsigned off, sl; float wgt;
    if (i < 2u * PO) { base = (i < PO) ? ep : ea; off = (i < PO) ? i : i - PO; sl = SL; wgt = wbig; }
    else             { base = ev; off = i - 2u * PO; sl = SLV; wgt = wsmall; }
    const uint4 u0 = *reinterpret_cast<const uint4*>(base + (size_t)off * 8);
    const uint4 u1 = *reinterpret_cast<const uint4*>(base + (size_t)(off + sl) * 8);
    float s = 0.f, d;
    d = b2f_lo(u1.x) - b2f_lo(u0.x); s += d * d;
    d = b2f_hi(u1.x) - b2f_hi(u0.x); s += d * d;
    d = b2f_lo(u1.y) - b2f_lo(u0.y); s += d * d;
    d = b2f_hi(u1.y) - b2f_hi(u0.y); s += d * d;
    d = b2f_lo(u1.z) - b2f_lo(u0.z); s += d * d;
    d = b2f_hi(u1.z) - b2f_hi(u0.z); s += d * d;
    d = b2f_lo(u1.w) - b2f_lo(u0.w); s += d * d;
    d = b2f_hi(u1.w) - b2f_hi(u0.w); s += d * d;
    local += wgt * s;
  }
  __shared__ float red[256];
  red[threadIdx.x] = local;
  __syncthreads();
  for (int s = 128; s > 0; s >>= 1) {
    if (threadIdx.x < s) red[threadIdx.x] += red[threadIdx.x + s];
    __syncthreads();
  }
  if (threadIdx.x == 0) partials[blockIdx.x] = red[0];
}

// ---------------------------------------------------------------------------
// v_all bf16: wave per n, lane handles 4 cols
// ---------------------------------------------------------------------------
__global__ __launch_bounds__(256) void vall_kernel(const unsigned short* __restrict__ ep,
                                                   const unsigned short* __restrict__ ea,
                                                   const unsigned short* __restrict__ ev,
                                                   const int* __restrict__ aidx,
                                                   const int* __restrict__ vidx,
                                                   const float* __restrict__ wm,
                                                   unsigned short* __restrict__ vall) {
  const int w = threadIdx.x >> 6, l = threadIdx.x & 63;
  const int n = blockIdx.x * 4 + w;
  float w0 = wm[0], w1 = wm[1], w2 = wm[2];
  const float mx = fmaxf(w0, fmaxf(w1, w2));
  const float e0 = expf(w0 - mx), e1 = expf(w1 - mx), e2 = expf(w2 - mx);
  const float inv = 1.f / (e0 + e1 + e2);
  w0 = e0 * inv; w1 = e1 * inv; w2 = e2 * inv;
  const int a0 = aidx[n * 4 + 0], a1 = aidx[n * 4 + 1];
  const int a2 = aidx[n * 4 + 2], a3 = aidx[n * 4 + 3];
  const int vn = vidx[n];
  const int cb = l * 4;
  for (int t = 0; t < 7; ++t) {
    const size_t tb = (size_t)t * NP * HH;
    const uint2 ua0 = *reinterpret_cast<const uint2*>(ea + tb + (size_t)a0 * HH + cb);
    const uint2 ua1 = *reinterpret_cast<const uint2*>(ea + tb + (size_t)a1 * HH + cb);
    const uint2 ua2 = *reinterpret_cast<const uint2*>(ea + tb + (size_t)a2 * HH + cb);
    const uint2 ua3 = *reinterpret_cast<const uint2*>(ea + tb + (size_t)a3 * HH + cb);
    const uint2 uv  = *reinterpret_cast<const uint2*>(ev + (size_t)t * NV * HH + (size_t)vn * HH + cb);
    const uint2 up  = *reinterpret_cast<const uint2*>(ep + tb + (size_t)n * HH + cb);
    float o[4];
    o[0] = w0 * 0.25f * (b2f_lo(ua0.x) + b2f_lo(ua1.x) + b2f_lo(ua2.x) + b2f_lo(ua3.x)) + w1 * b2f_lo(uv.x) + w2 * b2f_lo(up.x);
    o[1] = w0 * 0.25f * (b2f_hi(ua0.x) + b2f_hi(ua1.x) + b2f_hi(ua2.x) + b2f_hi(ua3.x)) + w1 * b2f_hi(uv.x) + w2 * b2f_hi(up.x);
    o[2] = w0 * 0.25f * (b2f_lo(ua0.y) + b2f_lo(ua1.y) + b2f_lo(ua2.y) + b2f_lo(ua3.y)) + w1 * b2f_lo(uv.y) + w2 * b2f_lo(up.y);
    o[3] = w0 * 0.25f * (b2f_hi(ua0.y) + b2f_hi(ua1.y) + b2f_hi(ua2.y) + b2f_hi(ua3.y)) + w1 * b2f_hi(uv.y) + w2 * b2f_hi(up.y);
    uint2 ov; ov.x = cvt2(o[0], o[1]); ov.y = cvt2(o[2], o[3]);
    *reinterpret_cast<uint2*>(vall + tb + (size_t)n * HH + cb) = ov;
  }
}

// ---------------------------------------------------------------------------
// GRU step 0 (h=0): H0 = (1 - sigmoid(gz)) * tanh(gn), elementwise from GX
// ---------------------------------------------------------------------------
__global__ __launch_bounds__(256) void gru_h0(const unsigned short* __restrict__ GX,
                                              unsigned short* __restrict__ H0) {
  const int idx = blockIdx.x * 256 + threadIdx.x;   // 48000*64 quads
  const int hrow = idx >> 6, jq = idx & 63;
  const int g = (hrow >= 32000) ? 2 : (hrow >= 16000 ? 1 : 0);
  const int n = hrow - g * 16000;
  const size_t gxrow = (size_t)(4 + g) * 16000 + n;
  const unsigned short* gp = GX + gxrow * 768 + jq * 4;
  const uint2 uz = *reinterpret_cast<const uint2*>(gp + 256);
  const uint2 un = *reinterpret_cast<const uint2*>(gp + 512);
  float h[4];
  h[0] = (1.f - sigm(b2f_lo(uz.x))) * tanhfast(b2f_lo(un.x));
  h[1] = (1.f - sigm(b2f_hi(uz.x))) * tanhfast(b2f_hi(un.x));
  h[2] = (1.f - sigm(b2f_lo(uz.y))) * tanhfast(b2f_lo(un.y));
  h[3] = (1.f - sigm(b2f_hi(uz.y))) * tanhfast(b2f_hi(un.y));
  uint2 o; o.x = cvt2(h[0], h[1]); o.y = cvt2(h[2], h[3]);
  *reinterpret_cast<uint2*>(H0 + (size_t)hrow * 256 + jq * 4) = o;
}

// ---------------------------------------------------------------------------
// GRU recurrent step l (1..4): acc = Hsrc @ Wh (K=256) for 3 gates;
// epilogue: gates from GX + acc -> Hdst. 512 thr, tile 128 rows x 128 j.
// ---------------------------------------------------------------------------
__global__ __launch_bounds__(512) void gru_hstep(const unsigned short* __restrict__ GX,
                                                 const unsigned short* __restrict__ W2t,
                                                 const unsigned short* __restrict__ Hsrc,
                                                 unsigned short* __restrict__ Hdst,
                                                 int lstep) {
  __shared__ __align__(16) unsigned short As[128 * 64];   // H rows x k
  __shared__ __align__(16) unsigned short Bs[384 * 64];   // (gate*128+jj) x k
  const int t = threadIdx.x, w = t >> 6, l = t & 63;
  const int work = xcd_swz(blockIdx.x, 93, 6);            // 750 = 8*93+6
  const int bx = work >> 1, jb = work & 1;
  const int m0 = bx * 128, j0 = jb * 128;
  const int g = bx / 125;
  const size_t gxRowBase = (size_t)(4 + g - lstep) * 16000 + (size_t)(m0 - g * 16000);
  const int srow = l >> 3;
  const int scol = ((l & 7) ^ srow) * 8;
  const int wr = w >> 2, wj = w & 3;
  const f32x4 zero = {0.f, 0.f, 0.f, 0.f};
  f32x4 acc[3][4][2];
#pragma unroll
  for (int gate = 0; gate < 3; ++gate)
#pragma unroll
    for (int mi = 0; mi < 4; ++mi)
#pragma unroll
      for (int nj = 0; nj < 2; ++nj) acc[gate][mi][nj] = zero;

#pragma unroll
  for (int c = 0; c < 4; ++c) {
    // A: 128 rows of Hsrc, k-chunk c
#pragma unroll
    for (int i = 0; i < 2; ++i) {
      const int seg = w * 2 + i;             // 16 segs x 8 rows
      gld16(Hsrc + (size_t)(m0 + 8 * seg + srow) * 256 + c * 64 + scol, (void*)(As + seg * 512));
    }
    // B: 384 gate-cols (3 gates x 128 j), Wh half of W2t (k offset 256)
#pragma unroll
    for (int i = 0; i < 6; ++i) {
      const int seg = w * 6 + i;             // 48 segs x 8 rows
      const int tilerow = 8 * seg + srow;
      const int gate = tilerow >> 7, jj = tilerow & 127;
      gld16(W2t + (size_t)(gate * 256 + j0 + jj) * 512 + 256 + c * 64 + scol,
            (void*)(Bs + seg * 512));
    }
    __syncthreads();
#pragma unroll
    for (int ks = 0; ks < 2; ++ks) {
      short8 av[4], bv[6];
#pragma unroll
      for (int mi = 0; mi < 4; ++mi) {
        const int r = wr * 64 + mi * 16 + (l & 15);
        const int slot = (ks * 4 + (l >> 4)) ^ (r & 7);
        av[mi] = *reinterpret_cast<const short8*>(As + r * 64 + slot * 8);
      }
#pragma unroll
      for (int q = 0; q < 6; ++q) {          // q = gate*2 + nj
        const int r = (q >> 1) * 128 + wj * 32 + (q & 1) * 16 + (l & 15);
        const int slot = (ks * 4 + (l >> 4)) ^ (r & 7);
        bv[q] = *reinterpret_cast<const short8*>(Bs + r * 64 + slot * 8);
      }
#pragma unroll
      for (int gate = 0; gate < 3; ++gate)
#pragma unroll
        for (int mi = 0; mi < 4; ++mi)
#pragma unroll
          for (int nj = 0; nj < 2; ++nj)
            acc[gate][mi][nj] = __builtin_amdgcn_mfma_f32_16x16x32_bf16(
                av[mi], bv[gate * 2 + nj], acc[gate][mi][nj], 0, 0, 0);
    }
    __syncthreads();
  }
  // epilogue: gates
#pragma unroll
  for (int mi = 0; mi < 4; ++mi) {
#pragma unroll
    for (int nj = 0; nj < 2; ++nj) {
      const int jcol = j0 + wj * 32 + nj * 16 + (l & 15);
#pragma unroll
      for (int e = 0; e < 4; ++e) {
        const int rib = wr * 64 + mi * 16 + (l >> 4) * 4 + e;
        const size_t hidx = (size_t)(m0 + rib) * 256 + jcol;
        const size_t gxoff = (gxRowBase + rib) * 768 + jcol;
        const float aR = acc[0][mi][nj][e] + b2f(GX[gxoff]);
        const float aZ = acc[1][mi][nj][e] + b2f(GX[gxoff + 256]);
        const float hn = acc[2][mi][nj][e];
        const float xn = b2f(GX[gxoff + 512]);
        const float rg = sigm(aR);
        const float zg = sigm(aZ);
        const float ng = tanhfast(xn + rg * hn);
        const float ho = b2f(Hsrc[hidx]);
        Hdst[hidx] = f2b((1.f - zg) * ng + zg * ho);
      }
    }
  }
}

// ---------------------------------------------------------------------------
// Survival head + per-row loss (H in bf16)
// ---------------------------------------------------------------------------
__device__ inline float softplusf(float x) { return x > 20.f ? x : log1pf(expf(x)); }

__global__ __launch_bounds__(256) void head_kernel(const unsigned short* __restrict__ Hbuf,
                                                   const float* __restrict__ We, const float* __restrict__ be,
                                                   const float* __restrict__ Wm, const float* __restrict__ bmu,
                                                   const float* __restrict__ Ws, const float* __restrict__ bsg,
                                                   const float* __restrict__ yt,
                                                   float* __restrict__ partials) {
  const int wave = threadIdx.x >> 6, lane = threadIdx.x & 63;
  const int b = blockIdx.x * 4 + wave;
  const unsigned short* hrow = Hbuf + (size_t)b * HH;
  float pe = 0.f, pm = 0.f, ps = 0.f;
#pragma unroll
  for (int c = 0; c < 4; ++c) {
    const int k = lane + 64 * c;
    const float hv = b2f(hrow[k]);
    pe += hv * We[k]; pm += hv * Wm[k]; ps += hv * Ws[k];
  }
#pragma unroll
  for (int s = 32; s > 0; s >>= 1) {
    pe += __shfl_down(pe, s);
    pm += __shfl_down(pm, s);
    ps += __shfl_down(ps, s);
  }
  __shared__ float red[4];
  if (lane == 0) {
    const float eta = softplusf(pe + be[0]);
    const float mu  = pm + bmu[0];
    const float sg  = softplusf(ps + bsg[0]) + 0.001f;
    const float inv = 1.f / (sg * 1.41421356237309515f);
    float prev = 0.f, loss = 0.f;
#pragma unroll
    for (int h = 1; h <= 5; ++h) {
      const float z  = (logf((float)h) - mu) * inv;
      const float yc = eta * 0.5f * (1.f + erff(z));
      const float yh = yc - prev; prev = yc;
      const float d  = log1pf(yt[(size_t)b * 5 + (h - 1)] + 1.0f) - log1pf(yh);
      loss += d * d;
    }
    red[wave] = loss;
  }
  __syncthreads();
  if (threadIdx.x == 0) partials[blockIdx.x] = red[0] + red[1] + red[2] + red[3];
}

__global__ __launch_bounds__(256) void final_kernel(const float* __restrict__ lt,
                                                    const float* __restrict__ lp,
                                                    float* __restrict__ out) {
  __shared__ float r1[256], r2[256];
  float s1 = 0.f, s2 = 0.f;
  for (int i = threadIdx.x; i < 1024; i += 256) s1 += lt[i];
  for (int i = threadIdx.x; i < 12000; i += 256) s2 += lp[i];
  r1[threadIdx.x] = s1; r2[threadIdx.x] = s2;
  __syncthreads();
  for (int s = 128; s > 0; s >>= 1) {
    if (threadIdx.x < s) { r1[threadIdx.x] += r1[threadIdx.x + s]; r2[threadIdx.x] += r2[threadIdx.x + s]; }
    __syncthreads();
  }
  if (threadIdx.x == 0) out[0] = r2[0] / 240000.f + 0.5f * r1[0];
}

// ---------------------------------------------------------------------------
extern "C" void kernel_launch(void* const* d_in, const int* in_sizes, int n_in,
                              void* d_out, int out_size, void* d_ws, size_t ws_size,
                              hipStream_t stream) {
  (void)in_sizes; (void)n_in; (void)out_size; (void)ws_size;
  const float* x_paper  = (const float*)d_in[0];
  const float* x_author = (const float*)d_in[1];
  const float* x_venue  = (const float*)d_in[2];
  const int*   aidx     = (const int*)d_in[3];
  const int*   vidx     = (const int*)d_in[4];
  const float* y_true   = (const float*)d_in[5];
  const float* W_paper  = (const float*)d_in[6];
  const float* b_paper  = (const float*)d_in[7];
  const float* W_author = (const float*)d_in[8];
  const float* b_author = (const float*)d_in[9];
  const float* W_venue  = (const float*)d_in[10];
  const float* b_venue  = (const float*)d_in[11];
  const float* w_meta   = (const float*)d_in[12];
  const float* Wx       = (const float*)d_in[13];
  const float* Wh       = (const float*)d_in[14];
  const float* b_gru    = (const float*)d_in[15];
  const float* W_eta    = (const float*)d_in[16];
  const float* b_eta    = (const float*)d_in[17];
  const float* W_mu     = (const float*)d_in[18];
  const float* b_mu     = (const float*)d_in[19];
  const float* W_sigma  = (const float*)d_in[20];
  const float* b_sigma  = (const float*)d_in[21];

  // ws layout (shorts). Persistent: va16, Hb0, Hb1, W2t, GX, then f32 partials.
  // ep/ea/ev/Wt* overlay the GX region (dead before gx_gemm writes it).
  unsigned short* p = (unsigned short*)d_ws;
  unsigned short* va16 = p;  p += (size_t)7 * NP * 256;      // 28,672,000
  unsigned short* Hb0  = p;  p += (size_t)48000 * 256;       // 12,288,000
  unsigned short* Hb1  = p;  p += (size_t)48000 * 256;       // 12,288,000
  unsigned short* W2t  = p;  p += (size_t)768 * 512;         //    393,216
  unsigned short* GX   = p;  p += (size_t)112000 * 768;      // 86,016,000
  float* ltp = (float*)p;
  float* lpp = ltp + 1024;
  // overlays (inside GX region):
  unsigned short* ep16 = GX;                                  // 32,768,000
  unsigned short* ea16 = ep16 + (size_t)8 * NP * 256;         // 32,768,000
  unsigned short* ev16 = ea16 + (size_t)8 * NP * 256;         //    409,600
  unsigned short* Wtp  = ev16 + (size_t)8 * NV * 256;
  unsigned short* Wta  = Wtp + 65536;
  unsigned short* Wtv  = Wta + 65536;

  // packs
  packWt<<<256, 256, 0, stream>>>(W_paper,  Wtp);
  packWt<<<256, 256, 0, stream>>>(W_author, Wta);
  packWt<<<256, 256, 0, stream>>>(W_venue,  Wtv);
  packW2t<<<768, 256, 0, stream>>>(Wx, Wh, W2t);

  // embeddings (fp32 in, bf16 out); grids: 2000 (q=250,r=0), 26 (q=3,r=2)
  embed_f32<<<2000, 256, 0, stream>>>(x_paper,  Wtp, b_paper,  ep16, 8 * NP, 250, 0);
  embed_f32<<<2000, 256, 0, stream>>>(x_author, Wta, b_author, ea16, 8 * NP, 250, 0);
  embed_f32<<<26,   256, 0, stream>>>(x_venue,  Wtv, b_venue,  ev16, 8 * NV, 3, 2);

  ltime_kernel<<<1024, 256, 0, stream>>>(ep16, ea16, ev16, ltp);
  vall_kernel<<<NP / 4, 256, 0, stream>>>(ep16, ea16, ev16, aidx, vidx, w_meta, va16);

  // GX = vall @ Wx + b_gru   (clobbers ep/ea/ev/Wt* — all dead now)
  gx_gemm<<<5250, 256, 0, stream>>>(va16, W2t, b_gru, GX);

  // GRU: step0 elementwise, then 4 recurrent MFMA steps (ping-pong)
  gru_h0<<<12000, 256, 0, stream>>>(GX, Hb0);
  gru_hstep<<<750, 512, 0, stream>>>(GX, W2t, Hb0, Hb1, 1);
  gru_hstep<<<750, 512, 0, stream>>>(GX, W2t, Hb1, Hb0, 2);
  gru_hstep<<<750, 512, 0, stream>>>(GX, W2t, Hb0, Hb1, 3);
  gru_hstep<<<750, 512, 0, stream>>>(GX, W2t, Hb1, Hb0, 4);

  head_kernel<<<12000, 256, 0, stream>>>(Hb0, W_eta, b_eta, W_mu, b_mu, W_sigma, b_sigma,
                                         y_true, lpp);
  final_kernel<<<1, 256, 0, stream>>>(ltp, lpp, (float*)d_out);
}

// Round 4
// 613.594 us; speedup vs baseline: 7.6146x; 1.1564x over previous
//
#include <hip/hip_runtime.h>
#include <cmath>

#define NP  16000
#define NV  200
#define HH  256

typedef short short8 __attribute__((ext_vector_type(8)));
typedef float f32x4  __attribute__((ext_vector_type(4)));

__device__ __forceinline__ unsigned short f2b(float f) {
  union { float f; unsigned u; } x; x.f = f;
  unsigned r = x.u + 0x7fffu + ((x.u >> 16) & 1u);
  return (unsigned short)(r >> 16);
}
__device__ __forceinline__ float b2f(unsigned short h) {
  union { unsigned u; float f; } x; x.u = ((unsigned)h) << 16;
  return x.f;
}
__device__ __forceinline__ float b2f_lo(unsigned u) {
  union { unsigned v; float f; } x; x.v = u << 16; return x.f;
}
__device__ __forceinline__ float b2f_hi(unsigned u) {
  union { unsigned v; float f; } x; x.v = u & 0xffff0000u; return x.f;
}
// pack 2 f32 -> 2 bf16 (RNE) in one instr
__device__ __forceinline__ unsigned cvt2(float a, float b) {
  unsigned r;
  asm("v_cvt_pk_bf16_f32 %0, %1, %2" : "=v"(r) : "v"(a), "v"(b));
  return r;
}
__device__ __forceinline__ void gld16(const void* g, void* l) {
  __builtin_amdgcn_global_load_lds((const __attribute__((address_space(1))) void*)g,
                                   (__attribute__((address_space(3))) void*)l, 16, 0, 0);
}
__device__ __forceinline__ float sigm(float x) { return 1.f / (1.f + __expf(-x)); }
__device__ __forceinline__ float tanhfast(float x) {
  const float e = __expf(-2.f * fabsf(x));
  const float t = (1.f - e) / (1.f + e);
  return x < 0.f ? -t : t;
}
// bijective chunked XCD swizzle (m204): orig -> work, nwg = 8q + r
__device__ __forceinline__ int xcd_swz(int orig, int q, int r) {
  const int xcd = orig & 7, loc = orig >> 3;
  return (xcd < r ? xcd * (q + 1) : r * (q + 1) + (xcd - r) * q) + loc;
}

// ---------------------------------------------------------------------------
// Weight packs
// W (256x256 fp32, [k][n]) -> Wt bf16 [n][k]
__global__ __launch_bounds__(256) void packWt(const float* __restrict__ W,
                                              unsigned short* __restrict__ Wt) {
  const int n = blockIdx.x, k = threadIdx.x;
  Wt[n * 256 + k] = f2b(W[k * 256 + n]);
}
// Wx (256x768), Wh (256x768) -> W2t bf16 [col 768][k 512] (k<256: Wx, else Wh)
__global__ __launch_bounds__(256) void packW2t(const float* __restrict__ Wx,
                                               const float* __restrict__ Wh,
                                               unsigned short* __restrict__ W2t) {
  const int col = blockIdx.x;
  for (int k = threadIdx.x; k < 512; k += 256)
    W2t[(size_t)col * 512 + k] =
        f2b(k < 256 ? Wx[(size_t)k * 768 + col] : Wh[(size_t)(k - 256) * 768 + col]);
}

// ---------------------------------------------------------------------------
// Embed GEMM: E = relu(Xf32 @ W + b), tile 128x128, BK=64, K=256.
// A reg-staged fp32->bf16 into swizzled LDS; B gld16 (pre-swizzled source).
// ---------------------------------------------------------------------------
__global__ __launch_bounds__(256) void embed_f32(const float* __restrict__ Xf,
                                                 const unsigned short* __restrict__ Wt,
                                                 const float* __restrict__ bias,
                                                 unsigned short* __restrict__ E,
                                                 int M, int swq, int swr) {
  __shared__ __align__(16) unsigned short As[128 * 64];
  __shared__ __align__(16) unsigned short Bs[128 * 64];
  const int t = threadIdx.x, w = t >> 6, l = t & 63;
  const int work = xcd_swz(blockIdx.x, swq, swr);
  const int m0 = (work >> 1) * 128, n0 = (work & 1) * 128;
  const int srow = l >> 3;
  const int scol = ((l & 7) ^ srow) * 8;
  const f32x4 zero = {0.f, 0.f, 0.f, 0.f};
  f32x4 acc[4][4];
#pragma unroll
  for (int i = 0; i < 4; ++i)
#pragma unroll
    for (int j = 0; j < 4; ++j) acc[i][j] = zero;
  const int mrow0 = 64 * (w >> 1), ncol0 = 64 * (w & 1);

#pragma unroll
  for (int c = 0; c < 4; ++c) {
    // A: reg-stage 128x64 fp32 -> bf16 swizzled LDS
#pragma unroll
    for (int a = 0; a < 2; ++a) {
      const int idx = t * 2 + a;            // 0..511
      const int row = idx >> 2, cg = idx & 3;
      const int grow = min(m0 + row, M - 1);
      const float4* s = reinterpret_cast<const float4*>(Xf + (size_t)grow * 256 + c * 64 + cg * 16);
      const float4 f0 = s[0], f1 = s[1], f2 = s[2], f3 = s[3];
      uint4 u0, u1;
      u0.x = cvt2(f0.x, f0.y); u0.y = cvt2(f0.z, f0.w);
      u0.z = cvt2(f1.x, f1.y); u0.w = cvt2(f1.z, f1.w);
      u1.x = cvt2(f2.x, f2.y); u1.y = cvt2(f2.z, f2.w);
      u1.z = cvt2(f3.x, f3.y); u1.w = cvt2(f3.z, f3.w);
      const int s0 = (cg * 2) ^ (row & 7), s1 = (cg * 2 + 1) ^ (row & 7);
      *reinterpret_cast<uint4*>(As + row * 64 + s0 * 8) = u0;
      *reinterpret_cast<uint4*>(As + row * 64 + s1 * 8) = u1;
    }
    // B: gld16, pre-swizzled source
#pragma unroll
    for (int i = 0; i < 4; ++i) {
      const int seg = 4 * w + i;
      gld16(Wt + (size_t)(n0 + 8 * seg + srow) * 256 + c * 64 + scol, (void*)(Bs + seg * 512));
    }
    __syncthreads();
#pragma unroll
    for (int ks = 0; ks < 2; ++ks) {
      short8 av[4], bv[4];
#pragma unroll
      for (int mi = 0; mi < 4; ++mi) {
        const int r = mrow0 + mi * 16 + (l & 15);
        const int slot = (ks * 4 + (l >> 4)) ^ (r & 7);
        av[mi] = *reinterpret_cast<const short8*>(As + r * 64 + slot * 8);
      }
#pragma unroll
      for (int nj = 0; nj < 4; ++nj) {
        const int r = ncol0 + nj * 16 + (l & 15);
        const int slot = (ks * 4 + (l >> 4)) ^ (r & 7);
        bv[nj] = *reinterpret_cast<const short8*>(Bs + r * 64 + slot * 8);
      }
#pragma unroll
      for (int mi = 0; mi < 4; ++mi)
#pragma unroll
        for (int nj = 0; nj < 4; ++nj)
          acc[mi][nj] = __builtin_amdgcn_mfma_f32_16x16x32_bf16(av[mi], bv[nj], acc[mi][nj], 0, 0, 0);
    }
    __syncthreads();
  }
#pragma unroll
  for (int nj = 0; nj < 4; ++nj) {
    const int colg = n0 + ncol0 + nj * 16 + (l & 15);
    const float bv = bias[colg];
#pragma unroll
    for (int mi = 0; mi < 4; ++mi) {
      const int rbase = m0 + mrow0 + mi * 16 + (l >> 4) * 4;
#pragma unroll
      for (int e = 0; e < 4; ++e) {
        const int row = rbase + e;
        if (row < M) E[(size_t)row * 256 + colg] = f2b(fmaxf(acc[mi][nj][e] + bv, 0.f));
      }
    }
  }
}

// ---------------------------------------------------------------------------
// GX GEMM: GX = vall @ Wx + b_gru  (M=112000, N=768, K=256), bf16 out.
// ---------------------------------------------------------------------------
__global__ __launch_bounds__(256) void gx_gemm(const unsigned short* __restrict__ Abf,
                                               const unsigned short* __restrict__ W2t,
                                               const float* __restrict__ bias,
                                               unsigned short* __restrict__ GX) {
  __shared__ __align__(16) unsigned short As[128 * 64];
  __shared__ __align__(16) unsigned short Bs[128 * 64];
  const int t = threadIdx.x, w = t >> 6, l = t & 63;
  const int work = xcd_swz(blockIdx.x, 656, 2);
  const int m0 = (work / 6) * 128, n0 = (work % 6) * 128;
  const int srow = l >> 3;
  const int scol = ((l & 7) ^ srow) * 8;
  const f32x4 zero = {0.f, 0.f, 0.f, 0.f};
  f32x4 acc[4][4];
#pragma unroll
  for (int i = 0; i < 4; ++i)
#pragma unroll
    for (int j = 0; j < 4; ++j) acc[i][j] = zero;
  const int mrow0 = 64 * (w >> 1), ncol0 = 64 * (w & 1);

#pragma unroll
  for (int c = 0; c < 4; ++c) {
#pragma unroll
    for (int i = 0; i < 4; ++i) {
      const int seg = 4 * w + i;
      gld16(Abf + (size_t)(m0 + 8 * seg + srow) * 256 + c * 64 + scol, (void*)(As + seg * 512));
    }
#pragma unroll
    for (int i = 0; i < 4; ++i) {
      const int seg = 4 * w + i;
      gld16(W2t + (size_t)(n0 + 8 * seg + srow) * 512 + c * 64 + scol, (void*)(Bs + seg * 512));
    }
    __syncthreads();
#pragma unroll
    for (int ks = 0; ks < 2; ++ks) {
      short8 av[4], bv[4];
#pragma unroll
      for (int mi = 0; mi < 4; ++mi) {
        const int r = mrow0 + mi * 16 + (l & 15);
        const int slot = (ks * 4 + (l >> 4)) ^ (r & 7);
        av[mi] = *reinterpret_cast<const short8*>(As + r * 64 + slot * 8);
      }
#pragma unroll
      for (int nj = 0; nj < 4; ++nj) {
        const int r = ncol0 + nj * 16 + (l & 15);
        const int slot = (ks * 4 + (l >> 4)) ^ (r & 7);
        bv[nj] = *reinterpret_cast<const short8*>(Bs + r * 64 + slot * 8);
      }
#pragma unroll
      for (int mi = 0; mi < 4; ++mi)
#pragma unroll
        for (int nj = 0; nj < 4; ++nj)
          acc[mi][nj] = __builtin_amdgcn_mfma_f32_16x16x32_bf16(av[mi], bv[nj], acc[mi][nj], 0, 0, 0);
    }
    __syncthreads();
  }
#pragma unroll
  for (int nj = 0; nj < 4; ++nj) {
    const int colg = n0 + ncol0 + nj * 16 + (l & 15);
    const float bv = bias[colg];
#pragma unroll
    for (int mi = 0; mi < 4; ++mi) {
      const int rbase = m0 + mrow0 + mi * 16 + (l >> 4) * 4;
#pragma unroll
      for (int e = 0; e < 4; ++e)
        GX[(size_t)(rbase + e) * 768 + colg] = f2b(acc[mi][nj][e] + bv);
    }
  }
}

// ---------------------------------------------------------------------------
// l_time from bf16 embeddings
// ---------------------------------------------------------------------------
__global__ __launch_bounds__(256) void ltime_kernel(const unsigned short* __restrict__ ep,
                                                    const unsigned short* __restrict__ ea,
                                                    const unsigned short* __restrict__ ev,
                                                    float* __restrict__ partials) {
  const unsigned PO = 3584000u, VO = 44800u;
  const unsigned TOT = 2u * PO + VO;
  const unsigned SL = 512000u, SLV = 6400u;
  const float wbig = 1.f / (3.f * 7.f * 16000.f);
  const float wsmall = 1.f / (3.f * 7.f * 200.f);
  float local = 0.f;
  for (unsigned i = blockIdx.x * 256u + threadIdx.x; i < TOT; i += gridDim.x * 256u) {
    const unsigned short* base; unsigned off, sl; float wgt;
    if (i < 2u * PO) { base = (i < PO) ? ep : ea; off = (i < PO) ? i : i - PO; sl = SL; wgt = wbig; }
    else             { base = ev; off = i - 2u * PO; sl = SLV; wgt = wsmall; }
    const uint4 u0 = *reinterpret_cast<const uint4*>(base + (size_t)off * 8);
    const uint4 u1 = *reinterpret_cast<const uint4*>(base + (size_t)(off + sl) * 8);
    float s = 0.f, d;
    d = b2f_lo(u1.x) - b2f_lo(u0.x); s += d * d;
    d = b2f_hi(u1.x) - b2f_hi(u0.x); s += d * d;
    d = b2f_lo(u1.y) - b2f_lo(u0.y); s += d * d;
    d = b2f_hi(u1.y) - b2f_hi(u0.y); s += d * d;
    d = b2f_lo(u1.z) - b2f_lo(u0.z); s += d * d;
    d = b2f_hi(u1.z) - b2f_hi(u0.z); s += d * d;
    d = b2f_lo(u1.w) - b2f_lo(u0.w); s += d * d;
    d = b2f_hi(u1.w) - b2f_hi(u0.w); s += d * d;
    local += wgt * s;
  }
  __shared__ float red[256];
  red[threadIdx.x] = local;
  __syncthreads();
  for (int s = 128; s > 0; s >>= 1) {
    if (threadIdx.x < s) red[threadIdx.x] += red[threadIdx.x + s];
    __syncthreads();
  }
  if (threadIdx.x == 0) partials[blockIdx.x] = red[0];
}

// ---------------------------------------------------------------------------
// v_all bf16: wave per n, lane handles 4 cols
// ---------------------------------------------------------------------------
__global__ __launch_bounds__(256) void vall_kernel(const unsigned short* __restrict__ ep,
                                                   const unsigned short* __restrict__ ea,
                                                   const unsigned short* __restrict__ ev,
                                                   const int* __restrict__ aidx,
                                                   const int* __restrict__ vidx,
                                                   const float* __restrict__ wm,
                                                   unsigned short* __restrict__ vall) {
  const int w = threadIdx.x >> 6, l = threadIdx.x & 63;
  const int n = blockIdx.x * 4 + w;
  float w0 = wm[0], w1 = wm[1], w2 = wm[2];
  const float mx = fmaxf(w0, fmaxf(w1, w2));
  const float e0 = expf(w0 - mx), e1 = expf(w1 - mx), e2 = expf(w2 - mx);
  const float inv = 1.f / (e0 + e1 + e2);
  w0 = e0 * inv; w1 = e1 * inv; w2 = e2 * inv;
  const int a0 = aidx[n * 4 + 0], a1 = aidx[n * 4 + 1];
  const int a2 = aidx[n * 4 + 2], a3 = aidx[n * 4 + 3];
  const int vn = vidx[n];
  const int cb = l * 4;
  for (int t = 0; t < 7; ++t) {
    const size_t tb = (size_t)t * NP * HH;
    const uint2 ua0 = *reinterpret_cast<const uint2*>(ea + tb + (size_t)a0 * HH + cb);
    const uint2 ua1 = *reinterpret_cast<const uint2*>(ea + tb + (size_t)a1 * HH + cb);
    const uint2 ua2 = *reinterpret_cast<const uint2*>(ea + tb + (size_t)a2 * HH + cb);
    const uint2 ua3 = *reinterpret_cast<const uint2*>(ea + tb + (size_t)a3 * HH + cb);
    const uint2 uv  = *reinterpret_cast<const uint2*>(ev + (size_t)t * NV * HH + (size_t)vn * HH + cb);
    const uint2 up  = *reinterpret_cast<const uint2*>(ep + tb + (size_t)n * HH + cb);
    float o[4];
    o[0] = w0 * 0.25f * (b2f_lo(ua0.x) + b2f_lo(ua1.x) + b2f_lo(ua2.x) + b2f_lo(ua3.x)) + w1 * b2f_lo(uv.x) + w2 * b2f_lo(up.x);
    o[1] = w0 * 0.25f * (b2f_hi(ua0.x) + b2f_hi(ua1.x) + b2f_hi(ua2.x) + b2f_hi(ua3.x)) + w1 * b2f_hi(uv.x) + w2 * b2f_hi(up.x);
    o[2] = w0 * 0.25f * (b2f_lo(ua0.y) + b2f_lo(ua1.y) + b2f_lo(ua2.y) + b2f_lo(ua3.y)) + w1 * b2f_lo(uv.y) + w2 * b2f_lo(up.y);
    o[3] = w0 * 0.25f * (b2f_hi(ua0.y) + b2f_hi(ua1.y) + b2f_hi(ua2.y) + b2f_hi(ua3.y)) + w1 * b2f_hi(uv.y) + w2 * b2f_hi(up.y);
    uint2 ov; ov.x = cvt2(o[0], o[1]); ov.y = cvt2(o[2], o[3]);
    *reinterpret_cast<uint2*>(vall + tb + (size_t)n * HH + cb) = ov;
  }
}

// ---------------------------------------------------------------------------
// GRU step 0 (h=0): H0 = (1 - sigmoid(gz)) * tanh(gn), elementwise from GX
// ---------------------------------------------------------------------------
__global__ __launch_bounds__(256) void gru_h0(const unsigned short* __restrict__ GX,
                                              unsigned short* __restrict__ H0) {
  const int idx = blockIdx.x * 256 + threadIdx.x;   // 48000*64 quads
  const int hrow = idx >> 6, jq = idx & 63;
  const int g = (hrow >= 32000) ? 2 : (hrow >= 16000 ? 1 : 0);
  const int n = hrow - g * 16000;
  const size_t gxrow = (size_t)(4 + g) * 16000 + n;
  const unsigned short* gp = GX + gxrow * 768 + jq * 4;
  const uint2 uz = *reinterpret_cast<const uint2*>(gp + 256);
  const uint2 un = *reinterpret_cast<const uint2*>(gp + 512);
  float h[4];
  h[0] = (1.f - sigm(b2f_lo(uz.x))) * tanhfast(b2f_lo(un.x));
  h[1] = (1.f - sigm(b2f_hi(uz.x))) * tanhfast(b2f_hi(un.x));
  h[2] = (1.f - sigm(b2f_lo(uz.y))) * tanhfast(b2f_lo(un.y));
  h[3] = (1.f - sigm(b2f_hi(uz.y))) * tanhfast(b2f_hi(un.y));
  uint2 o; o.x = cvt2(h[0], h[1]); o.y = cvt2(h[2], h[3]);
  *reinterpret_cast<uint2*>(H0 + (size_t)hrow * 256 + jq * 4) = o;
}

// ---------------------------------------------------------------------------
// GRU recurrent step l (1..4): acc = Hsrc @ Wh (K=256) for 3 gates;
// epilogue: gates from GX + acc -> Hdst. 512 thr, tile 128 rows x 128 j.
// ---------------------------------------------------------------------------
__global__ __launch_bounds__(512) void gru_hstep(const unsigned short* __restrict__ GX,
                                                 const unsigned short* __restrict__ W2t,
                                                 const unsigned short* __restrict__ Hsrc,
                                                 unsigned short* __restrict__ Hdst,
                                                 int lstep) {
  __shared__ __align__(16) unsigned short As[128 * 64];   // H rows x k
  __shared__ __align__(16) unsigned short Bs[384 * 64];   // (gate*128+jj) x k
  const int t = threadIdx.x, w = t >> 6, l = t & 63;
  const int work = xcd_swz(blockIdx.x, 93, 6);            // 750 = 8*93+6
  const int bx = work >> 1, jb = work & 1;
  const int m0 = bx * 128, j0 = jb * 128;
  const int g = bx / 125;
  const size_t gxRowBase = (size_t)(4 + g - lstep) * 16000 + (size_t)(m0 - g * 16000);
  const int srow = l >> 3;
  const int scol = ((l & 7) ^ srow) * 8;
  const int wr = w >> 2, wj = w & 3;
  const f32x4 zero = {0.f, 0.f, 0.f, 0.f};
  f32x4 acc[3][4][2];
#pragma unroll
  for (int gate = 0; gate < 3; ++gate)
#pragma unroll
    for (int mi = 0; mi < 4; ++mi)
#pragma unroll
      for (int nj = 0; nj < 2; ++nj) acc[gate][mi][nj] = zero;

#pragma unroll
  for (int c = 0; c < 4; ++c) {
#pragma unroll
    for (int i = 0; i < 2; ++i) {
      const int seg = w * 2 + i;             // 16 segs x 8 rows
      gld16(Hsrc + (size_t)(m0 + 8 * seg + srow) * 256 + c * 64 + scol, (void*)(As + seg * 512));
    }
#pragma unroll
    for (int i = 0; i < 6; ++i) {
      const int seg = w * 6 + i;             // 48 segs x 8 rows
      const int tilerow = 8 * seg + srow;
      const int gate = tilerow >> 7, jj = tilerow & 127;
      gld16(W2t + (size_t)(gate * 256 + j0 + jj) * 512 + 256 + c * 64 + scol,
            (void*)(Bs + seg * 512));
    }
    __syncthreads();
#pragma unroll
    for (int ks = 0; ks < 2; ++ks) {
      short8 av[4], bv[6];
#pragma unroll
      for (int mi = 0; mi < 4; ++mi) {
        const int r = wr * 64 + mi * 16 + (l & 15);
        const int slot = (ks * 4 + (l >> 4)) ^ (r & 7);
        av[mi] = *reinterpret_cast<const short8*>(As + r * 64 + slot * 8);
      }
#pragma unroll
      for (int q = 0; q < 6; ++q) {          // q = gate*2 + nj
        const int r = (q >> 1) * 128 + wj * 32 + (q & 1) * 16 + (l & 15);
        const int slot = (ks * 4 + (l >> 4)) ^ (r & 7);
        bv[q] = *reinterpret_cast<const short8*>(Bs + r * 64 + slot * 8);
      }
#pragma unroll
      for (int gate = 0; gate < 3; ++gate)
#pragma unroll
        for (int mi = 0; mi < 4; ++mi)
#pragma unroll
          for (int nj = 0; nj < 2; ++nj)
            acc[gate][mi][nj] = __builtin_amdgcn_mfma_f32_16x16x32_bf16(
                av[mi], bv[gate * 2 + nj], acc[gate][mi][nj], 0, 0, 0);
    }
    __syncthreads();
  }
  // epilogue: gates
#pragma unroll
  for (int mi = 0; mi < 4; ++mi) {
#pragma unroll
    for (int nj = 0; nj < 2; ++nj) {
      const int jcol = j0 + wj * 32 + nj * 16 + (l & 15);
#pragma unroll
      for (int e = 0; e < 4; ++e) {
        const int rib = wr * 64 + mi * 16 + (l >> 4) * 4 + e;
        const size_t hidx = (size_t)(m0 + rib) * 256 + jcol;
        const size_t gxoff = (gxRowBase + rib) * 768 + jcol;
        const float aR = acc[0][mi][nj][e] + b2f(GX[gxoff]);
        const float aZ = acc[1][mi][nj][e] + b2f(GX[gxoff + 256]);
        const float hn = acc[2][mi][nj][e];
        const float xn = b2f(GX[gxoff + 512]);
        const float rg = sigm(aR);
        const float zg = sigm(aZ);
        const float ng = tanhfast(xn + rg * hn);
        const float ho = b2f(Hsrc[hidx]);
        Hdst[hidx] = f2b((1.f - zg) * ng + zg * ho);
      }
    }
  }
}

// ---------------------------------------------------------------------------
// Survival head + per-row loss: THREAD per row (lane-parallel transcendentals)
// ---------------------------------------------------------------------------
__device__ inline float softplusf(float x) { return x > 20.f ? x : log1pf(expf(x)); }

__global__ __launch_bounds__(256) void head_kernel(const unsigned short* __restrict__ Hbuf,
                                                   const float* __restrict__ We, const float* __restrict__ be,
                                                   const float* __restrict__ Wm, const float* __restrict__ bmu,
                                                   const float* __restrict__ Ws, const float* __restrict__ bsg,
                                                   const float* __restrict__ yt,
                                                   float* __restrict__ partials) {
  __shared__ float sWe[256], sWm[256], sWs[256];
  const int t = threadIdx.x;
  sWe[t] = We[t]; sWm[t] = Wm[t]; sWs[t] = Ws[t];
  __syncthreads();
  const int row = blockIdx.x * 256 + t;
  float loss = 0.f;
  if (row < 48000) {
    const unsigned short* h = Hbuf + (size_t)row * HH;
    float pe = 0.f, pm = 0.f, ps = 0.f;
#pragma unroll 4
    for (int k0 = 0; k0 < 256; k0 += 8) {
      const uint4 u = *reinterpret_cast<const uint4*>(h + k0);
      const float hv[8] = {b2f_lo(u.x), b2f_hi(u.x), b2f_lo(u.y), b2f_hi(u.y),
                           b2f_lo(u.z), b2f_hi(u.z), b2f_lo(u.w), b2f_hi(u.w)};
#pragma unroll
      for (int q = 0; q < 8; ++q) {
        const int k = k0 + q;
        pe += hv[q] * sWe[k]; pm += hv[q] * sWm[k]; ps += hv[q] * sWs[k];
      }
    }
    const float eta = softplusf(pe + be[0]);
    const float mu  = pm + bmu[0];
    const float sg  = softplusf(ps + bsg[0]) + 0.001f;
    const float inv = 1.f / (sg * 1.41421356237309515f);
    float prev = 0.f;
#pragma unroll
    for (int hz = 1; hz <= 5; ++hz) {
      const float z  = (logf((float)hz) - mu) * inv;
      const float yc = eta * 0.5f * (1.f + erff(z));
      const float yh = yc - prev; prev = yc;
      const float d  = log1pf(yt[(size_t)row * 5 + (hz - 1)] + 1.0f) - log1pf(yh);
      loss += d * d;
    }
  }
  __shared__ float red[256];
  red[t] = loss;
  __syncthreads();
  for (int s = 128; s > 0; s >>= 1) {
    if (t < s) red[t] += red[t + s];
    __syncthreads();
  }
  if (t == 0) partials[blockIdx.x] = red[0];
}

__global__ __launch_bounds__(256) void final_kernel(const float* __restrict__ lt,
                                                    const float* __restrict__ lp,
                                                    float* __restrict__ out) {
  __shared__ float r1[256], r2[256];
  float s1 = 0.f, s2 = 0.f;
  for (int i = threadIdx.x; i < 1024; i += 256) s1 += lt[i];
  for (int i = threadIdx.x; i < 188; i += 256) s2 += lp[i];
  r1[threadIdx.x] = s1; r2[threadIdx.x] = s2;
  __syncthreads();
  for (int s = 128; s > 0; s >>= 1) {
    if (threadIdx.x < s) { r1[threadIdx.x] += r1[threadIdx.x + s]; r2[threadIdx.x] += r2[threadIdx.x + s]; }
    __syncthreads();
  }
  if (threadIdx.x == 0) out[0] = r2[0] / 240000.f + 0.5f * r1[0];
}

// ---------------------------------------------------------------------------
extern "C" void kernel_launch(void* const* d_in, const int* in_sizes, int n_in,
                              void* d_out, int out_size, void* d_ws, size_t ws_size,
                              hipStream_t stream) {
  (void)in_sizes; (void)n_in; (void)out_size; (void)ws_size;
  const float* x_paper  = (const float*)d_in[0];
  const float* x_author = (const float*)d_in[1];
  const float* x_venue  = (const float*)d_in[2];
  const int*   aidx     = (const int*)d_in[3];
  const int*   vidx     = (const int*)d_in[4];
  const float* y_true   = (const float*)d_in[5];
  const float* W_paper  = (const float*)d_in[6];
  const float* b_paper  = (const float*)d_in[7];
  const float* W_author = (const float*)d_in[8];
  const float* b_author = (const float*)d_in[9];
  const float* W_venue  = (const float*)d_in[10];
  const float* b_venue  = (const float*)d_in[11];
  const float* w_meta   = (const float*)d_in[12];
  const float* Wx       = (const float*)d_in[13];
  const float* Wh       = (const float*)d_in[14];
  const float* b_gru    = (const float*)d_in[15];
  const float* W_eta    = (const float*)d_in[16];
  const float* b_eta    = (const float*)d_in[17];
  const float* W_mu     = (const float*)d_in[18];
  const float* b_mu     = (const float*)d_in[19];
  const float* W_sigma  = (const float*)d_in[20];
  const float* b_sigma  = (const float*)d_in[21];

  // ws layout (shorts). Persistent: va16, Hb0, Hb1, W2t, GX, then f32 partials.
  unsigned short* p = (unsigned short*)d_ws;
  unsigned short* va16 = p;  p += (size_t)7 * NP * 256;      // 28,672,000
  unsigned short* Hb0  = p;  p += (size_t)48000 * 256;       // 12,288,000
  unsigned short* Hb1  = p;  p += (size_t)48000 * 256;       // 12,288,000
  unsigned short* W2t  = p;  p += (size_t)768 * 512;         //    393,216
  unsigned short* GX   = p;  p += (size_t)112000 * 768;      // 86,016,000
  float* ltp = (float*)p;
  float* lpp = ltp + 1024;
  // overlays (inside GX region):
  unsigned short* ep16 = GX;
  unsigned short* ea16 = ep16 + (size_t)8 * NP * 256;
  unsigned short* ev16 = ea16 + (size_t)8 * NP * 256;
  unsigned short* Wtp  = ev16 + (size_t)8 * NV * 256;
  unsigned short* Wta  = Wtp + 65536;
  unsigned short* Wtv  = Wta + 65536;

  // packs
  packWt<<<256, 256, 0, stream>>>(W_paper,  Wtp);
  packWt<<<256, 256, 0, stream>>>(W_author, Wta);
  packWt<<<256, 256, 0, stream>>>(W_venue,  Wtv);
  packW2t<<<768, 256, 0, stream>>>(Wx, Wh, W2t);

  // embeddings (fp32 in, bf16 out)
  embed_f32<<<2000, 256, 0, stream>>>(x_paper,  Wtp, b_paper,  ep16, 8 * NP, 250, 0);
  embed_f32<<<2000, 256, 0, stream>>>(x_author, Wta, b_author, ea16, 8 * NP, 250, 0);
  embed_f32<<<26,   256, 0, stream>>>(x_venue,  Wtv, b_venue,  ev16, 8 * NV, 3, 2);

  ltime_kernel<<<1024, 256, 0, stream>>>(ep16, ea16, ev16, ltp);
  vall_kernel<<<NP / 4, 256, 0, stream>>>(ep16, ea16, ev16, aidx, vidx, w_meta, va16);

  // GX = vall @ Wx + b_gru
  gx_gemm<<<5250, 256, 0, stream>>>(va16, W2t, b_gru, GX);

  // GRU: step0 elementwise, then 4 recurrent MFMA steps (ping-pong)
  gru_h0<<<12000, 256, 0, stream>>>(GX, Hb0);
  gru_hstep<<<750, 512, 0, stream>>>(GX, W2t, Hb0, Hb1, 1);
  gru_hstep<<<750, 512, 0, stream>>>(GX, W2t, Hb1, Hb0, 2);
  gru_hstep<<<750, 512, 0, stream>>>(GX, W2t, Hb0, Hb1, 3);
  gru_hstep<<<750, 512, 0, stream>>>(GX, W2t, Hb1, Hb0, 4);

  head_kernel<<<188, 256, 0, stream>>>(Hb0, W_eta, b_eta, W_mu, b_mu, W_sigma, b_sigma,
                                       y_true, lpp);
  final_kernel<<<1, 256, 0, stream>>>(ltp, lpp, (float*)d_out);
}